// Round 1
// baseline (6227.665 us; speedup 1.0000x reference)
//
#include <hip/hip_runtime.h>

#define MODS 4
#define CH   128
#define NHD  4
#define HDIM 32
#define NTOK 1728
#define NG   (NTOK/4)          // 432 groups of 4 tokens
#define INV_SCALE 0.17677669529663687f   // 1/sqrt(32)

// ---------------------------------------------------------------------------
// Kernel 1: QKV projections.
// Q/K/V layout in ws: [m][h][n][d]  (key rows of 32 floats contiguous)
// thread -> (t in {Q,K,V}, m, o, n4); computes 4 consecutive tokens for one o.
// ---------------------------------------------------------------------------
__global__ __launch_bounds__(256) void proj_kernel(
    const float* __restrict__ f0, const float* __restrict__ f1,
    const float* __restrict__ f2, const float* __restrict__ f3,
    const float* __restrict__ Wq, const float* __restrict__ Wk,
    const float* __restrict__ Wv,
    float* __restrict__ Qb, float* __restrict__ Kb, float* __restrict__ Vb)
{
    int idx = blockIdx.x * blockDim.x + threadIdx.x;
    if (idx >= 3 * MODS * CH * NG) return;
    int n4 = idx % NG;
    int o  = (idx / NG) % CH;
    int m  = (idx / (NG * CH)) % MODS;
    int t  = idx / (NG * CH * MODS);

    const float* fs = (m == 0) ? f0 : (m == 1) ? f1 : (m == 2) ? f2 : f3;
    const float* W  = ((t == 0) ? Wq : (t == 1) ? Wk : Wv) + ((size_t)m * CH + o) * CH;
    float* outp     = (t == 0) ? Qb : (t == 1) ? Kb : Vb;

    const float* fbase = fs + n4 * 4;
    float a0 = 0.f, a1 = 0.f, a2 = 0.f, a3 = 0.f;
    #pragma unroll 8
    for (int c = 0; c < CH; c += 4) {
        float4 w4 = *reinterpret_cast<const float4*>(W + c);
        float4 r0 = *reinterpret_cast<const float4*>(fbase + (size_t)(c + 0) * NTOK);
        float4 r1 = *reinterpret_cast<const float4*>(fbase + (size_t)(c + 1) * NTOK);
        float4 r2 = *reinterpret_cast<const float4*>(fbase + (size_t)(c + 2) * NTOK);
        float4 r3 = *reinterpret_cast<const float4*>(fbase + (size_t)(c + 3) * NTOK);
        a0 = fmaf(w4.x, r0.x, a0); a0 = fmaf(w4.y, r1.x, a0); a0 = fmaf(w4.z, r2.x, a0); a0 = fmaf(w4.w, r3.x, a0);
        a1 = fmaf(w4.x, r0.y, a1); a1 = fmaf(w4.y, r1.y, a1); a1 = fmaf(w4.z, r2.y, a1); a1 = fmaf(w4.w, r3.y, a1);
        a2 = fmaf(w4.x, r0.z, a2); a2 = fmaf(w4.y, r1.z, a2); a2 = fmaf(w4.z, r2.z, a2); a2 = fmaf(w4.w, r3.z, a2);
        a3 = fmaf(w4.x, r0.w, a3); a3 = fmaf(w4.y, r1.w, a3); a3 = fmaf(w4.z, r2.w, a3); a3 = fmaf(w4.w, r3.w, a3);
    }
    int h = o >> 5, d = o & 31;
    float* op = outp + ((size_t)(m * NHD + h) * NTOK + n4 * 4) * HDIM + d;
    op[0 * HDIM] = a0; op[1 * HDIM] = a1; op[2 * HDIM] = a2; op[3 * HDIM] = a3;
}

// ---------------------------------------------------------------------------
// Kernel 2: cross-modal attention. One wave per (head h, query token q).
// Keys (m*N+n) strided across 64 lanes. No max-subtraction needed: logits
// are O(1..35), exp stays comfortably inside fp32 range -> identical softmax.
// fused layout: [c = h*32+d][n]
// ---------------------------------------------------------------------------
__global__ __launch_bounds__(256) void attn_kernel(
    const float* __restrict__ Qb, const float* __restrict__ Kb,
    const float* __restrict__ Vb, float* __restrict__ fused)
{
    int wid  = blockIdx.x * 4 + (threadIdx.x >> 6);
    int lane = threadIdx.x & 63;
    int h = wid & (NHD - 1);
    int q = wid >> 2;

    float fsel = 0.f;
    for (int i = 0; i < MODS; ++i) {
        const float* Qrow = Qb + ((size_t)(i * NHD + h) * NTOK + q) * HDIM;
        float qr[HDIM];
        #pragma unroll
        for (int g = 0; g < 8; ++g) {
            float4 t = *reinterpret_cast<const float4*>(Qrow + 4 * g);
            qr[4*g+0] = t.x; qr[4*g+1] = t.y; qr[4*g+2] = t.z; qr[4*g+3] = t.w;
        }
        float s = 0.f;
        float acc[HDIM];
        #pragma unroll
        for (int d = 0; d < HDIM; ++d) acc[d] = 0.f;

        for (int km = 0; km < MODS; ++km) {
            const float* Kbase = Kb + (size_t)(km * NHD + h) * NTOK * HDIM;
            const float* Vbase = Vb + (size_t)(km * NHD + h) * NTOK * HDIM;
            for (int kn = lane; kn < NTOK; kn += 64) {
                const float* kr = Kbase + (size_t)kn * HDIM;
                float dot = 0.f;
                #pragma unroll
                for (int g = 0; g < 8; ++g) {
                    float4 kk = *reinterpret_cast<const float4*>(kr + 4 * g);
                    dot = fmaf(qr[4*g+0], kk.x, dot);
                    dot = fmaf(qr[4*g+1], kk.y, dot);
                    dot = fmaf(qr[4*g+2], kk.z, dot);
                    dot = fmaf(qr[4*g+3], kk.w, dot);
                }
                float p = __expf(dot * INV_SCALE);
                s += p;
                const float* vr = Vbase + (size_t)kn * HDIM;
                #pragma unroll
                for (int g = 0; g < 8; ++g) {
                    float4 vv = *reinterpret_cast<const float4*>(vr + 4 * g);
                    acc[4*g+0] = fmaf(p, vv.x, acc[4*g+0]);
                    acc[4*g+1] = fmaf(p, vv.y, acc[4*g+1]);
                    acc[4*g+2] = fmaf(p, vv.z, acc[4*g+2]);
                    acc[4*g+3] = fmaf(p, vv.w, acc[4*g+3]);
                }
            }
        }
        // wave all-reduce of s and acc[0..31]
        #pragma unroll
        for (int off = 32; off > 0; off >>= 1) {
            s += __shfl_xor(s, off, 64);
            #pragma unroll
            for (int d = 0; d < HDIM; ++d) acc[d] += __shfl_xor(acc[d], off, 64);
        }
        float r = 1.0f / s;
        // lane l (l<32) keeps acc[l] -- static-index select chain (no scratch)
        float sel = acc[0];
        #pragma unroll
        for (int d = 1; d < HDIM; ++d) sel = (lane == d) ? acc[d] : sel;
        fsel = fmaf(sel, r, fsel);
    }
    if (lane < HDIM) fused[(size_t)(h * HDIM + lane) * NTOK + q] = fsel;
}

// ---------------------------------------------------------------------------
// Kernel 3: out-proj (Wout @ fused) + BatchNorm(eval) + ReLU
// ---------------------------------------------------------------------------
__global__ __launch_bounds__(256) void outproj_kernel(
    const float* __restrict__ fused, const float* __restrict__ Wout,
    const float* __restrict__ gamma, const float* __restrict__ beta,
    const float* __restrict__ mean,  const float* __restrict__ var,
    float* __restrict__ out)
{
    int idx = blockIdx.x * blockDim.x + threadIdx.x;
    if (idx >= CH * NG) return;
    int n4 = idx % NG;
    int o  = idx / NG;
    const float* W     = Wout + (size_t)o * CH;
    const float* fbase = fused + n4 * 4;
    float a0 = 0.f, a1 = 0.f, a2 = 0.f, a3 = 0.f;
    #pragma unroll 8
    for (int c = 0; c < CH; c += 4) {
        float4 w4 = *reinterpret_cast<const float4*>(W + c);
        float4 r0 = *reinterpret_cast<const float4*>(fbase + (size_t)(c + 0) * NTOK);
        float4 r1 = *reinterpret_cast<const float4*>(fbase + (size_t)(c + 1) * NTOK);
        float4 r2 = *reinterpret_cast<const float4*>(fbase + (size_t)(c + 2) * NTOK);
        float4 r3 = *reinterpret_cast<const float4*>(fbase + (size_t)(c + 3) * NTOK);
        a0 = fmaf(w4.x, r0.x, a0); a0 = fmaf(w4.y, r1.x, a0); a0 = fmaf(w4.z, r2.x, a0); a0 = fmaf(w4.w, r3.x, a0);
        a1 = fmaf(w4.x, r0.y, a1); a1 = fmaf(w4.y, r1.y, a1); a1 = fmaf(w4.z, r2.y, a1); a1 = fmaf(w4.w, r3.y, a1);
        a2 = fmaf(w4.x, r0.z, a2); a2 = fmaf(w4.y, r1.z, a2); a2 = fmaf(w4.z, r2.z, a2); a2 = fmaf(w4.w, r3.z, a2);
        a3 = fmaf(w4.x, r0.w, a3); a3 = fmaf(w4.y, r1.w, a3); a3 = fmaf(w4.z, r2.w, a3); a3 = fmaf(w4.w, r3.w, a3);
    }
    float inv = gamma[o] * rsqrtf(var[o] + 1e-5f);
    float sh  = fmaf(-mean[o], inv, beta[o]);
    float4 y;
    y.x = fmaxf(fmaf(a0, inv, sh), 0.f);
    y.y = fmaxf(fmaf(a1, inv, sh), 0.f);
    y.z = fmaxf(fmaf(a2, inv, sh), 0.f);
    y.w = fmaxf(fmaf(a3, inv, sh), 0.f);
    *reinterpret_cast<float4*>(out + (size_t)o * NTOK + n4 * 4) = y;
}

// ---------------------------------------------------------------------------
extern "C" void kernel_launch(void* const* d_in, const int* in_sizes, int n_in,
                              void* d_out, int out_size, void* d_ws, size_t ws_size,
                              hipStream_t stream)
{
    const float* f0    = (const float*)d_in[0];
    const float* f1    = (const float*)d_in[1];
    const float* f2    = (const float*)d_in[2];
    const float* f3    = (const float*)d_in[3];
    const float* Wq    = (const float*)d_in[4];
    const float* Wk    = (const float*)d_in[5];
    const float* Wv    = (const float*)d_in[6];
    const float* Wout  = (const float*)d_in[7];
    const float* gamma = (const float*)d_in[8];
    const float* beta  = (const float*)d_in[9];
    const float* mean  = (const float*)d_in[10];
    const float* var   = (const float*)d_in[11];
    float* out = (float*)d_out;

    const size_t QKV = (size_t)MODS * NHD * NTOK * HDIM;   // 884736 floats
    float* ws    = (float*)d_ws;
    float* Qb    = ws;
    float* Kb    = ws + QKV;
    float* Vb    = ws + 2 * QKV;
    float* fused = ws + 3 * QKV;   // CH * NTOK floats

    proj_kernel<<<(3 * MODS * CH * NG) / 256, 256, 0, stream>>>(
        f0, f1, f2, f3, Wq, Wk, Wv, Qb, Kb, Vb);
    attn_kernel<<<(NHD * NTOK) / 4, 256, 0, stream>>>(Qb, Kb, Vb, fused);
    outproj_kernel<<<(CH * NG) / 256, 256, 0, stream>>>(
        fused, Wout, gamma, beta, mean, var, out);
}

// Round 2
// 628.279 us; speedup vs baseline: 9.9123x; 9.9123x over previous
//
#include <hip/hip_runtime.h>

#define MODS 4
#define CH   128
#define NHD  4
#define HDIM 32
#define NTOK 1728
#define NG   (NTOK/4)
#define NKEY (MODS*NTOK)        // 6912
#define TQ   64
#define TK   64
#define NQT  (NKEY/TQ)          // 108 query tiles per head
#define NKT  (NKEY/TK)          // 108 key tiles
#define INV_SCALE 0.17677669529663687f   // 1/sqrt(32)

// ---------------------------------------------------------------------------
// Kernel 1: QKV projections.  Q/K/V layout in ws: [m][h][n][d]
// ---------------------------------------------------------------------------
__global__ __launch_bounds__(256) void proj_kernel(
    const float* __restrict__ f0, const float* __restrict__ f1,
    const float* __restrict__ f2, const float* __restrict__ f3,
    const float* __restrict__ Wq, const float* __restrict__ Wk,
    const float* __restrict__ Wv,
    float* __restrict__ Qb, float* __restrict__ Kb, float* __restrict__ Vb)
{
    int idx = blockIdx.x * blockDim.x + threadIdx.x;
    if (idx >= 3 * MODS * CH * NG) return;
    int n4 = idx % NG;
    int o  = (idx / NG) % CH;
    int m  = (idx / (NG * CH)) % MODS;
    int t  = idx / (NG * CH * MODS);

    const float* fs = (m == 0) ? f0 : (m == 1) ? f1 : (m == 2) ? f2 : f3;
    const float* W  = ((t == 0) ? Wq : (t == 1) ? Wk : Wv) + ((size_t)m * CH + o) * CH;
    float* outp     = (t == 0) ? Qb : (t == 1) ? Kb : Vb;

    const float* fbase = fs + n4 * 4;
    float a0 = 0.f, a1 = 0.f, a2 = 0.f, a3 = 0.f;
    #pragma unroll 8
    for (int c = 0; c < CH; c += 4) {
        float4 w4 = *reinterpret_cast<const float4*>(W + c);
        float4 r0 = *reinterpret_cast<const float4*>(fbase + (size_t)(c + 0) * NTOK);
        float4 r1 = *reinterpret_cast<const float4*>(fbase + (size_t)(c + 1) * NTOK);
        float4 r2 = *reinterpret_cast<const float4*>(fbase + (size_t)(c + 2) * NTOK);
        float4 r3 = *reinterpret_cast<const float4*>(fbase + (size_t)(c + 3) * NTOK);
        a0 = fmaf(w4.x, r0.x, a0); a0 = fmaf(w4.y, r1.x, a0); a0 = fmaf(w4.z, r2.x, a0); a0 = fmaf(w4.w, r3.x, a0);
        a1 = fmaf(w4.x, r0.y, a1); a1 = fmaf(w4.y, r1.y, a1); a1 = fmaf(w4.z, r2.y, a1); a1 = fmaf(w4.w, r3.y, a1);
        a2 = fmaf(w4.x, r0.z, a2); a2 = fmaf(w4.y, r1.z, a2); a2 = fmaf(w4.z, r2.z, a2); a2 = fmaf(w4.w, r3.z, a2);
        a3 = fmaf(w4.x, r0.w, a3); a3 = fmaf(w4.y, r1.w, a3); a3 = fmaf(w4.z, r2.w, a3); a3 = fmaf(w4.w, r3.w, a3);
    }
    int h = o >> 5, d = o & 31;
    float* op = outp + ((size_t)(m * NHD + h) * NTOK + n4 * 4) * HDIM + d;
    op[0 * HDIM] = a0; op[1 * HDIM] = a1; op[2 * HDIM] = a2; op[3 * HDIM] = a3;
}

// ---------------------------------------------------------------------------
// Kernel 2: LDS-tiled cross-modal attention.
// Block = (head h, 64-query tile). 256 threads (4 waves).
// GEMM1: S[64q][64k] via 4x4 register tiles from Qs/Ks (both [d][.]).
// exp in regs -> Ps[k][q] (transposed, padded). GEMM2: acc[4q][4d] over
// half the keys per wave-pair (rep), combined at the end via LDS.
// Softmax is max-free (logits O(10), fp32-safe -> identical result).
// out4 layout: [c][n][i]  (i = query modality) so outproj sums with float4.
// ---------------------------------------------------------------------------
__global__ __launch_bounds__(256) void attn_kernel(
    const float* __restrict__ Qb, const float* __restrict__ Kb,
    const float* __restrict__ Vb, float* __restrict__ out4)
{
    __shared__ __align__(16) float Qs[HDIM][TQ];   // 8 KB
    __shared__ __align__(16) float Ks[HDIM][TK];   // 8 KB
    __shared__ __align__(16) float Vs[TK][36];     // 9 KB  (pad 36)
    __shared__ __align__(16) float Ps[TK][72];     // 18 KB (pad 72)
    __shared__ __align__(16) float Sred[TQ];       // 256 B

    const int t   = threadIdx.x;
    const int bid = blockIdx.x;
    const int g   = (bid & 7) * ((NHD * NQT) >> 3) + (bid >> 3); // XCD chunks
    const int h   = g / NQT;
    const int qt  = g % NQT;
    const int qg0 = qt * TQ;           // global query index base (this head)
    const int im  = qg0 / NTOK;        // query modality (tile inside one mod)
    const int n0  = qg0 % NTOK;

    // --- stage Q tile transposed: Qs[d][q] ---
    {
        const int qq = t & 63, dg = (t >> 6) * 8;
        const float* qp = Qb + (((size_t)(im * NHD + h)) * NTOK + n0 + qq) * HDIM + dg;
        float4 v0 = *reinterpret_cast<const float4*>(qp);
        float4 v1 = *reinterpret_cast<const float4*>(qp + 4);
        Qs[dg+0][qq]=v0.x; Qs[dg+1][qq]=v0.y; Qs[dg+2][qq]=v0.z; Qs[dg+3][qq]=v0.w;
        Qs[dg+4][qq]=v1.x; Qs[dg+5][qq]=v1.y; Qs[dg+6][qq]=v1.z; Qs[dg+7][qq]=v1.w;
    }

    const int tk  = t & 15,  tq  = t >> 4;          // GEMM1: k'=4tk, q'=4tq
    const int td2 = t & 7,   tq2 = (t >> 3) & 15;   // GEMM2: d'=4td2, q'=4tq2
    const int rep = t >> 7;                         // k-half (waves 0,1 / 2,3)

    float ssum[4] = {0.f, 0.f, 0.f, 0.f};
    float acc[4][4] = {};

    for (int kt = 0; kt < NKT; ++kt) {
        __syncthreads();   // prev GEMM2 done reading Ps/Vs (and Q stage on it 0)
        // --- stage K (transposed) and V (row-major, padded) ---
        {
            const int kk = t & 63, dg = (t >> 6) * 8;
            const int kg = kt * TK + kk;
            const int km = kg / NTOK, kn = kg % NTOK;
            const size_t off = (((size_t)(km * NHD + h)) * NTOK + kn) * HDIM + dg;
            float4 k0 = *reinterpret_cast<const float4*>(Kb + off);
            float4 k1 = *reinterpret_cast<const float4*>(Kb + off + 4);
            float4 w0 = *reinterpret_cast<const float4*>(Vb + off);
            float4 w1 = *reinterpret_cast<const float4*>(Vb + off + 4);
            Ks[dg+0][kk]=k0.x; Ks[dg+1][kk]=k0.y; Ks[dg+2][kk]=k0.z; Ks[dg+3][kk]=k0.w;
            Ks[dg+4][kk]=k1.x; Ks[dg+5][kk]=k1.y; Ks[dg+6][kk]=k1.z; Ks[dg+7][kk]=k1.w;
            *reinterpret_cast<float4*>(&Vs[kk][dg])     = w0;
            *reinterpret_cast<float4*>(&Vs[kk][dg + 4]) = w1;
        }
        __syncthreads();

        // --- GEMM1: Sv[j][l] = sum_d Q[q0+j][d] * K[k0+l][d] ---
        float Sv[4][4] = {};
        #pragma unroll 8
        for (int d = 0; d < HDIM; ++d) {
            float4 a = *reinterpret_cast<const float4*>(&Qs[d][4 * tq]);
            float4 b = *reinterpret_cast<const float4*>(&Ks[d][4 * tk]);
            Sv[0][0] = fmaf(a.x, b.x, Sv[0][0]); Sv[0][1] = fmaf(a.x, b.y, Sv[0][1]);
            Sv[0][2] = fmaf(a.x, b.z, Sv[0][2]); Sv[0][3] = fmaf(a.x, b.w, Sv[0][3]);
            Sv[1][0] = fmaf(a.y, b.x, Sv[1][0]); Sv[1][1] = fmaf(a.y, b.y, Sv[1][1]);
            Sv[1][2] = fmaf(a.y, b.z, Sv[1][2]); Sv[1][3] = fmaf(a.y, b.w, Sv[1][3]);
            Sv[2][0] = fmaf(a.z, b.x, Sv[2][0]); Sv[2][1] = fmaf(a.z, b.y, Sv[2][1]);
            Sv[2][2] = fmaf(a.z, b.z, Sv[2][2]); Sv[2][3] = fmaf(a.z, b.w, Sv[2][3]);
            Sv[3][0] = fmaf(a.w, b.x, Sv[3][0]); Sv[3][1] = fmaf(a.w, b.y, Sv[3][1]);
            Sv[3][2] = fmaf(a.w, b.z, Sv[3][2]); Sv[3][3] = fmaf(a.w, b.w, Sv[3][3]);
        }
        // --- exp + row-sum partials + store P transposed: Ps[k][q] ---
        #pragma unroll
        for (int l = 0; l < 4; ++l) {
            float4 p;
            p.x = __expf(Sv[0][l] * INV_SCALE);
            p.y = __expf(Sv[1][l] * INV_SCALE);
            p.z = __expf(Sv[2][l] * INV_SCALE);
            p.w = __expf(Sv[3][l] * INV_SCALE);
            ssum[0] += p.x; ssum[1] += p.y; ssum[2] += p.z; ssum[3] += p.w;
            *reinterpret_cast<float4*>(&Ps[4 * tk + l][4 * tq]) = p;
        }
        __syncthreads();

        // --- GEMM2: acc[j][l] += sum_k Ps[k][q0+j] * Vs[k][d0+l] ---
        #pragma unroll 8
        for (int kk2 = 0; kk2 < 32; ++kk2) {
            const int k = (rep << 5) + kk2;
            float4 p = *reinterpret_cast<const float4*>(&Ps[k][4 * tq2]);
            float4 v = *reinterpret_cast<const float4*>(&Vs[k][4 * td2]);
            acc[0][0] = fmaf(p.x, v.x, acc[0][0]); acc[0][1] = fmaf(p.x, v.y, acc[0][1]);
            acc[0][2] = fmaf(p.x, v.z, acc[0][2]); acc[0][3] = fmaf(p.x, v.w, acc[0][3]);
            acc[1][0] = fmaf(p.y, v.x, acc[1][0]); acc[1][1] = fmaf(p.y, v.y, acc[1][1]);
            acc[1][2] = fmaf(p.y, v.z, acc[1][2]); acc[1][3] = fmaf(p.y, v.w, acc[1][3]);
            acc[2][0] = fmaf(p.z, v.x, acc[2][0]); acc[2][1] = fmaf(p.z, v.y, acc[2][1]);
            acc[2][2] = fmaf(p.z, v.z, acc[2][2]); acc[2][3] = fmaf(p.z, v.w, acc[2][3]);
            acc[3][0] = fmaf(p.w, v.x, acc[3][0]); acc[3][1] = fmaf(p.w, v.y, acc[3][1]);
            acc[3][2] = fmaf(p.w, v.z, acc[3][2]); acc[3][3] = fmaf(p.w, v.w, acc[3][3]);
        }
    }

    // --- row-sum reduce across the 16 tk threads (same wave, xor<16) ---
    #pragma unroll
    for (int off = 1; off < 16; off <<= 1) {
        ssum[0] += __shfl_xor(ssum[0], off, 64);
        ssum[1] += __shfl_xor(ssum[1], off, 64);
        ssum[2] += __shfl_xor(ssum[2], off, 64);
        ssum[3] += __shfl_xor(ssum[3], off, 64);
    }
    if (tk == 0) {
        Sred[4*tq+0] = ssum[0]; Sred[4*tq+1] = ssum[1];
        Sred[4*tq+2] = ssum[2]; Sred[4*tq+3] = ssum[3];
    }
    // --- combine the two k-halves (reuse Qs as 64x32 scratch) ---
    float* Accs = &Qs[0][0];
    if (rep == 1) {
        #pragma unroll
        for (int j = 0; j < 4; ++j) {
            float4 v; v.x = acc[j][0]; v.y = acc[j][1]; v.z = acc[j][2]; v.w = acc[j][3];
            *reinterpret_cast<float4*>(&Accs[(4 * tq2 + j) * HDIM + 4 * td2]) = v;
        }
    }
    __syncthreads();
    if (rep == 0) {
        #pragma unroll
        for (int j = 0; j < 4; ++j) {
            const int qq = 4 * tq2 + j;
            const float r = 1.0f / Sred[qq];
            #pragma unroll
            for (int l = 0; l < 4; ++l) {
                float vsum = acc[j][l] + Accs[qq * HDIM + 4 * td2 + l];
                const size_t c = (size_t)(h * HDIM + 4 * td2 + l);
                out4[(c * NTOK + (n0 + qq)) * MODS + im] = vsum * r;
            }
        }
    }
}

// ---------------------------------------------------------------------------
// Kernel 3: out-proj (+ modality-sum) + BatchNorm(eval) + ReLU
// ---------------------------------------------------------------------------
__global__ __launch_bounds__(256) void outproj_kernel(
    const float* __restrict__ out4, const float* __restrict__ Wout,
    const float* __restrict__ gamma, const float* __restrict__ beta,
    const float* __restrict__ mean,  const float* __restrict__ var,
    float* __restrict__ out)
{
    int idx = blockIdx.x * blockDim.x + threadIdx.x;
    if (idx >= CH * NG) return;
    int n4 = idx % NG;
    int o  = idx / NG;
    const float* W = Wout + (size_t)o * CH;
    float a0 = 0.f, a1 = 0.f, a2 = 0.f, a3 = 0.f;
    #pragma unroll 4
    for (int c = 0; c < CH; ++c) {
        float w = W[c];
        const float* fb = out4 + ((size_t)c * NTOK + n4 * 4) * MODS;
        float4 v0 = *reinterpret_cast<const float4*>(fb + 0);
        float4 v1 = *reinterpret_cast<const float4*>(fb + 4);
        float4 v2 = *reinterpret_cast<const float4*>(fb + 8);
        float4 v3 = *reinterpret_cast<const float4*>(fb + 12);
        a0 = fmaf(w, (v0.x + v0.y) + (v0.z + v0.w), a0);
        a1 = fmaf(w, (v1.x + v1.y) + (v1.z + v1.w), a1);
        a2 = fmaf(w, (v2.x + v2.y) + (v2.z + v2.w), a2);
        a3 = fmaf(w, (v3.x + v3.y) + (v3.z + v3.w), a3);
    }
    float inv = gamma[o] * rsqrtf(var[o] + 1e-5f);
    float sh  = fmaf(-mean[o], inv, beta[o]);
    float4 y;
    y.x = fmaxf(fmaf(a0, inv, sh), 0.f);
    y.y = fmaxf(fmaf(a1, inv, sh), 0.f);
    y.z = fmaxf(fmaf(a2, inv, sh), 0.f);
    y.w = fmaxf(fmaf(a3, inv, sh), 0.f);
    *reinterpret_cast<float4*>(out + (size_t)o * NTOK + n4 * 4) = y;
}

// ---------------------------------------------------------------------------
extern "C" void kernel_launch(void* const* d_in, const int* in_sizes, int n_in,
                              void* d_out, int out_size, void* d_ws, size_t ws_size,
                              hipStream_t stream)
{
    const float* f0    = (const float*)d_in[0];
    const float* f1    = (const float*)d_in[1];
    const float* f2    = (const float*)d_in[2];
    const float* f3    = (const float*)d_in[3];
    const float* Wq    = (const float*)d_in[4];
    const float* Wk    = (const float*)d_in[5];
    const float* Wv    = (const float*)d_in[6];
    const float* Wout  = (const float*)d_in[7];
    const float* gamma = (const float*)d_in[8];
    const float* beta  = (const float*)d_in[9];
    const float* mean  = (const float*)d_in[10];
    const float* var   = (const float*)d_in[11];
    float* out = (float*)d_out;

    const size_t QKV = (size_t)MODS * NHD * NTOK * HDIM;   // 884736 floats
    float* ws   = (float*)d_ws;
    float* Qb   = ws;
    float* Kb   = ws + QKV;
    float* Vb   = ws + 2 * QKV;
    float* out4 = ws + 3 * QKV;   // [CH][NTOK][MODS] = 884736 floats

    proj_kernel<<<(3 * MODS * CH * NG) / 256, 256, 0, stream>>>(
        f0, f1, f2, f3, Wq, Wk, Wv, Qb, Kb, Vb);
    attn_kernel<<<NHD * NQT, 256, 0, stream>>>(Qb, Kb, Vb, out4);
    outproj_kernel<<<(CH * NG) / 256, 256, 0, stream>>>(
        out4, Wout, gamma, beta, mean, var, out);
}

// Round 4
// 223.409 us; speedup vs baseline: 27.8757x; 2.8122x over previous
//
#include <hip/hip_runtime.h>

#define MODS 4
#define CH   128
#define NHD  4
#define HDIM 32
#define NTOK 1728
#define NG   (NTOK/4)
#define NKEY (MODS*NTOK)        // 6912
#define INV_SCALE 0.17677669529663687f   // 1/sqrt(32)

typedef __bf16 bf16x8 __attribute__((ext_vector_type(8)));
typedef float  f32x16 __attribute__((ext_vector_type(16)));
typedef unsigned int u32x4 __attribute__((ext_vector_type(4)));

__device__ inline unsigned short f2bf(float x) {
    unsigned int u = __float_as_uint(x);
    unsigned int r = (u + 0x7FFFu + ((u >> 16) & 1u)) >> 16;   // RNE
    return (unsigned short)r;
}
__device__ inline unsigned int pk2(float lo, float hi) {
    return (unsigned int)f2bf(lo) | ((unsigned int)f2bf(hi) << 16);
}
__device__ inline bf16x8 ldb8(const unsigned short* p) {
    return *reinterpret_cast<const bf16x8*>(p);
}

// ---------------------------------------------------------------------------
// Kernel 1: QKV projections (fp32 math), bf16 outputs.
// Qb/Kb: bf16 [m][h][n][32] row-major.  Vt: bf16 [h][32d][m*1728+n].
// ---------------------------------------------------------------------------
__global__ __launch_bounds__(256) void proj_kernel(
    const float* __restrict__ f0, const float* __restrict__ f1,
    const float* __restrict__ f2, const float* __restrict__ f3,
    const float* __restrict__ Wq, const float* __restrict__ Wk,
    const float* __restrict__ Wv,
    unsigned short* __restrict__ Qb, unsigned short* __restrict__ Kb,
    unsigned short* __restrict__ Vt)
{
    int idx = blockIdx.x * blockDim.x + threadIdx.x;
    if (idx >= 3 * MODS * CH * NG) return;
    int n4 = idx % NG;
    int o  = (idx / NG) % CH;
    int m  = (idx / (NG * CH)) % MODS;
    int t  = idx / (NG * CH * MODS);

    const float* fs = (m == 0) ? f0 : (m == 1) ? f1 : (m == 2) ? f2 : f3;
    const float* W  = ((t == 0) ? Wq : (t == 1) ? Wk : Wv) + ((size_t)m * CH + o) * CH;

    const float* fbase = fs + n4 * 4;
    float a0 = 0.f, a1 = 0.f, a2 = 0.f, a3 = 0.f;
    #pragma unroll 8
    for (int c = 0; c < CH; c += 4) {
        float4 w4 = *reinterpret_cast<const float4*>(W + c);
        float4 r0 = *reinterpret_cast<const float4*>(fbase + (size_t)(c + 0) * NTOK);
        float4 r1 = *reinterpret_cast<const float4*>(fbase + (size_t)(c + 1) * NTOK);
        float4 r2 = *reinterpret_cast<const float4*>(fbase + (size_t)(c + 2) * NTOK);
        float4 r3 = *reinterpret_cast<const float4*>(fbase + (size_t)(c + 3) * NTOK);
        a0 = fmaf(w4.x, r0.x, a0); a0 = fmaf(w4.y, r1.x, a0); a0 = fmaf(w4.z, r2.x, a0); a0 = fmaf(w4.w, r3.x, a0);
        a1 = fmaf(w4.x, r0.y, a1); a1 = fmaf(w4.y, r1.y, a1); a1 = fmaf(w4.z, r2.y, a1); a1 = fmaf(w4.w, r3.y, a1);
        a2 = fmaf(w4.x, r0.z, a2); a2 = fmaf(w4.y, r1.z, a2); a2 = fmaf(w4.z, r2.z, a2); a2 = fmaf(w4.w, r3.z, a2);
        a3 = fmaf(w4.x, r0.w, a3); a3 = fmaf(w4.y, r1.w, a3); a3 = fmaf(w4.z, r2.w, a3); a3 = fmaf(w4.w, r3.w, a3);
    }
    int h = o >> 5, d = o & 31;
    if (t == 2) {
        ushort4 pk;
        pk.x = f2bf(a0); pk.y = f2bf(a1); pk.z = f2bf(a2); pk.w = f2bf(a3);
        *reinterpret_cast<ushort4*>(Vt + (size_t)(h * HDIM + d) * NKEY + m * NTOK + n4 * 4) = pk;
    } else {
        unsigned short* dst = ((t == 0) ? Qb : Kb)
            + (((size_t)(m * NHD + h)) * NTOK + n4 * 4) * HDIM + d;
        dst[0]  = f2bf(a0); dst[32] = f2bf(a1);
        dst[64] = f2bf(a2); dst[96] = f2bf(a3);
    }
}

// ---------------------------------------------------------------------------
// Kernel 2: MFMA cross-modal attention. 512 thr = 8 waves.
// wave w: qt=w&1 (two 32q tiles -> 64q/block), kq=w>>1 (4-way key split,
// one modality per wave, 27 iters x 64 keys).
// Swapped QK^T: S^T = mfma(K, Q); lane (q=l&31, hi=l>>5) holds P for
// keys k(r,hi) = (r&3)+8*(r>>2)+4*hi  (HW-verified C/D layout).
// PV pairing trick: MFMA pairs A-element (hi,j) with B-element (hi,j),
// so ANY consistent (hi,j)->key bijection works. We use
//   g(hi,j) = (j&3) + 4*hi + 8*(j>>2)
// which is EXACTLY the key set this lane already holds -> no cross-lane
// data movement (no permlane), no LDS in the k-loop. V fragments load the
// matching interleaved pattern as two 8-byte reads per 16-key window.
// Max-free softmax => k-split partials combine by plain addition.
// ---------------------------------------------------------------------------
__global__ __launch_bounds__(512) void attn_kernel(
    const unsigned short* __restrict__ Qb, const unsigned short* __restrict__ Kb,
    const unsigned short* __restrict__ Vt, float* __restrict__ out4)
{
    __shared__ float accL[2][4][32][32];   // 32 KB
    __shared__ float sL[2][4][2][32];      // 2 KB

    const int tid  = threadIdx.x;
    const int lane = tid & 63;
    const int w    = tid >> 6;
    const int qt   = w & 1;
    const int kq   = w >> 1;
    const int l31  = lane & 31;
    const int hi   = lane >> 5;

    const int bid  = blockIdx.x;
    const int s8   = bid & 7;                 // XCD slot
    const int h    = s8 >> 1;                 // 2 XCDs per head
    const int qtile = (s8 & 1) * 54 + (bid >> 3);   // 0..107
    const int qg0  = qtile * 64 + qt * 32;
    const int im   = qg0 / NTOK;
    const int n0   = qg0 % NTOK;

    // Q fragments (kept in registers whole kernel)
    const unsigned short* qp = Qb + (((size_t)(im * NHD + h)) * NTOK + n0 + l31) * HDIM + hi * 8;
    const bf16x8 qf0 = ldb8(qp);        // d = 8hi + j
    const bf16x8 qf1 = ldb8(qp + 16);   // d = 16 + 8hi + j

    // K pointer: rows = keys of modality kq
    const unsigned short* kp = Kb + (((size_t)(kq * NHD + h)) * NTOK + l31) * HDIM + hi * 8;
    // V^T row for d = l31, this modality's keys; 4hi interleave offset
    const unsigned short* vrow = Vt + ((size_t)(h * HDIM + l31)) * NKEY + kq * NTOK + 4 * hi;

    f32x16 o_acc;
    #pragma unroll
    for (int r = 0; r < 16; ++r) o_acc[r] = 0.f;
    float s_part = 0.f;

    for (int it = 0; it < 27; ++it) {
        // ---- QK^T: two 32-key S^T tiles, K=32 via 2 chained MFMAs each ----
        bf16x8 k00 = ldb8(kp);          // tile0, d 0..15
        bf16x8 k01 = ldb8(kp + 16);     // tile0, d 16..31
        bf16x8 k10 = ldb8(kp + 1024);   // tile1 (keys +32)
        bf16x8 k11 = ldb8(kp + 1040);
        f32x16 c0, c1;
        #pragma unroll
        for (int r = 0; r < 16; ++r) { c0[r] = 0.f; c1[r] = 0.f; }
        c0 = __builtin_amdgcn_mfma_f32_32x32x16_bf16(k00, qf0, c0, 0, 0, 0);
        c0 = __builtin_amdgcn_mfma_f32_32x32x16_bf16(k01, qf1, c0, 0, 0, 0);
        c1 = __builtin_amdgcn_mfma_f32_32x32x16_bf16(k10, qf0, c1, 0, 0, 0);
        c1 = __builtin_amdgcn_mfma_f32_32x32x16_bf16(k11, qf1, c1, 0, 0, 0);

        // ---- softmax numerators (max-free) ----
        float e0[16], e1[16];
        #pragma unroll
        for (int r = 0; r < 16; ++r) {
            e0[r] = __expf(c0[r] * INV_SCALE); s_part += e0[r];
            e1[r] = __expf(c1[r] * INV_SCALE); s_part += e1[r];
        }

        // ---- pack P into A-fragments, pairing g(hi,j)=(j&3)+4hi+8(j>>2) ----
        // e[r] holds key (r&3)+8*(r>>2)+4hi, so adjacent pairs ARE the frag:
        u32x4 w0 = {pk2(e0[0],  e0[1]),  pk2(e0[2],  e0[3]),
                    pk2(e0[4],  e0[5]),  pk2(e0[6],  e0[7])};   // keys win 0-15
        u32x4 w1 = {pk2(e0[8],  e0[9]),  pk2(e0[10], e0[11]),
                    pk2(e0[12], e0[13]), pk2(e0[14], e0[15])};  // win 16-31
        u32x4 w2 = {pk2(e1[0],  e1[1]),  pk2(e1[2],  e1[3]),
                    pk2(e1[4],  e1[5]),  pk2(e1[6],  e1[7])};   // win 32-47
        u32x4 w3 = {pk2(e1[8],  e1[9]),  pk2(e1[10], e1[11]),
                    pk2(e1[12], e1[13]), pk2(e1[14], e1[15])};  // win 48-63
        bf16x8 pa0 = __builtin_bit_cast(bf16x8, w0);
        bf16x8 pa1 = __builtin_bit_cast(bf16x8, w1);
        bf16x8 pa2 = __builtin_bit_cast(bf16x8, w2);
        bf16x8 pa3 = __builtin_bit_cast(bf16x8, w3);

        // ---- V B-fragments with the SAME g pairing: per 16-key window,
        //      elems 0-3 = keys 16n+4hi.., elems 4-7 = keys 16n+8+4hi.. ----
        const unsigned short* vb = vrow + it * 64;
        #define VFRAG(nwin) __builtin_bit_cast(bf16x8, (u32x4){ \
            reinterpret_cast<const uint2*>(vb + 16*(nwin))->x, \
            reinterpret_cast<const uint2*>(vb + 16*(nwin))->y, \
            reinterpret_cast<const uint2*>(vb + 16*(nwin) + 8)->x, \
            reinterpret_cast<const uint2*>(vb + 16*(nwin) + 8)->y })
        bf16x8 v0 = VFRAG(0);
        bf16x8 v1 = VFRAG(1);
        bf16x8 v2 = VFRAG(2);
        bf16x8 v3 = VFRAG(3);
        #undef VFRAG
        o_acc = __builtin_amdgcn_mfma_f32_32x32x16_bf16(pa0, v0, o_acc, 0, 0, 0);
        o_acc = __builtin_amdgcn_mfma_f32_32x32x16_bf16(pa1, v1, o_acc, 0, 0, 0);
        o_acc = __builtin_amdgcn_mfma_f32_32x32x16_bf16(pa2, v2, o_acc, 0, 0, 0);
        o_acc = __builtin_amdgcn_mfma_f32_32x32x16_bf16(pa3, v3, o_acc, 0, 0, 0);

        kp += 64 * HDIM;   // +64 key rows
    }

    // ---- spill partials to LDS, combine the 4 k-splits, normalize ----
    #pragma unroll
    for (int r = 0; r < 16; ++r) {
        int qrow = (r & 3) + 8 * (r >> 2) + 4 * hi;
        accL[qt][kq][qrow][l31] = o_acc[r];
    }
    sL[qt][kq][hi][l31] = s_part;
    __syncthreads();

    {
        const int cqt = tid >> 8;          // 0..1
        const int q   = (tid >> 3) & 31;
        const int dg  = tid & 7;
        const int qg  = qtile * 64 + cqt * 32 + q;
        const int cim = qg / NTOK;
        const int cn  = qg % NTOK;
        float4 a0 = *reinterpret_cast<const float4*>(&accL[cqt][0][q][dg * 4]);
        float4 a1 = *reinterpret_cast<const float4*>(&accL[cqt][1][q][dg * 4]);
        float4 a2 = *reinterpret_cast<const float4*>(&accL[cqt][2][q][dg * 4]);
        float4 a3 = *reinterpret_cast<const float4*>(&accL[cqt][3][q][dg * 4]);
        float st = 0.f;
        #pragma unroll
        for (int k2 = 0; k2 < 4; ++k2) st += sL[cqt][k2][0][q] + sL[cqt][k2][1][q];
        float r = 1.0f / st;
        float vx = (a0.x + a1.x) + (a2.x + a3.x);
        float vy = (a0.y + a1.y) + (a2.y + a3.y);
        float vz = (a0.z + a1.z) + (a2.z + a3.z);
        float vw = (a0.w + a1.w) + (a2.w + a3.w);
        const int c = h * HDIM + dg * 4;
        out4[((size_t)(c + 0) * NTOK + cn) * MODS + cim] = vx * r;
        out4[((size_t)(c + 1) * NTOK + cn) * MODS + cim] = vy * r;
        out4[((size_t)(c + 2) * NTOK + cn) * MODS + cim] = vz * r;
        out4[((size_t)(c + 3) * NTOK + cn) * MODS + cim] = vw * r;
    }
}

// ---------------------------------------------------------------------------
// Kernel 3: out-proj (+ modality-sum) + BatchNorm(eval) + ReLU
// ---------------------------------------------------------------------------
__global__ __launch_bounds__(256) void outproj_kernel(
    const float* __restrict__ out4, const float* __restrict__ Wout,
    const float* __restrict__ gamma, const float* __restrict__ beta,
    const float* __restrict__ mean,  const float* __restrict__ var,
    float* __restrict__ out)
{
    int idx = blockIdx.x * blockDim.x + threadIdx.x;
    if (idx >= CH * NG) return;
    int n4 = idx % NG;
    int o  = idx / NG;
    const float* W = Wout + (size_t)o * CH;
    float a0 = 0.f, a1 = 0.f, a2 = 0.f, a3 = 0.f;
    #pragma unroll 4
    for (int c = 0; c < CH; ++c) {
        float w = W[c];
        const float* fb = out4 + ((size_t)c * NTOK + n4 * 4) * MODS;
        float4 v0 = *reinterpret_cast<const float4*>(fb + 0);
        float4 v1 = *reinterpret_cast<const float4*>(fb + 4);
        float4 v2 = *reinterpret_cast<const float4*>(fb + 8);
        float4 v3 = *reinterpret_cast<const float4*>(fb + 12);
        a0 = fmaf(w, (v0.x + v0.y) + (v0.z + v0.w), a0);
        a1 = fmaf(w, (v1.x + v1.y) + (v1.z + v1.w), a1);
        a2 = fmaf(w, (v2.x + v2.y) + (v2.z + v2.w), a2);
        a3 = fmaf(w, (v3.x + v3.y) + (v3.z + v3.w), a3);
    }
    float inv = gamma[o] * rsqrtf(var[o] + 1e-5f);
    float sh  = fmaf(-mean[o], inv, beta[o]);
    float4 y;
    y.x = fmaxf(fmaf(a0, inv, sh), 0.f);
    y.y = fmaxf(fmaf(a1, inv, sh), 0.f);
    y.z = fmaxf(fmaf(a2, inv, sh), 0.f);
    y.w = fmaxf(fmaf(a3, inv, sh), 0.f);
    *reinterpret_cast<float4*>(out + (size_t)o * NTOK + n4 * 4) = y;
}

// ---------------------------------------------------------------------------
extern "C" void kernel_launch(void* const* d_in, const int* in_sizes, int n_in,
                              void* d_out, int out_size, void* d_ws, size_t ws_size,
                              hipStream_t stream)
{
    const float* f0    = (const float*)d_in[0];
    const float* f1    = (const float*)d_in[1];
    const float* f2    = (const float*)d_in[2];
    const float* f3    = (const float*)d_in[3];
    const float* Wq    = (const float*)d_in[4];
    const float* Wk    = (const float*)d_in[5];
    const float* Wv    = (const float*)d_in[6];
    const float* Wout  = (const float*)d_in[7];
    const float* gamma = (const float*)d_in[8];
    const float* beta  = (const float*)d_in[9];
    const float* mean  = (const float*)d_in[10];
    const float* var   = (const float*)d_in[11];
    float* out = (float*)d_out;

    const size_t QKV = (size_t)MODS * NHD * NTOK * HDIM;   // 884736 elems
    unsigned short* Qb = (unsigned short*)d_ws;
    unsigned short* Kb = Qb + QKV;
    unsigned short* Vt = Kb + QKV;
    float* out4        = (float*)(Vt + QKV);   // [CH][NTOK][MODS] f32

    proj_kernel<<<(3 * MODS * CH * NG) / 256, 256, 0, stream>>>(
        f0, f1, f2, f3, Wq, Wk, Wv, Qb, Kb, Vt);
    attn_kernel<<<432, 512, 0, stream>>>(Qb, Kb, Vt, out4);
    outproj_kernel<<<(CH * NG) / 256, 256, 0, stream>>>(
        out4, Wout, gamma, beta, mean, var, out);
}

// Round 5
// 172.444 us; speedup vs baseline: 36.1140x; 1.2955x over previous
//
#include <hip/hip_runtime.h>

#define MODS 4
#define CH   128
#define NHD  4
#define HDIM 32
#define NTOK 1728
#define NG   (NTOK/4)
#define NKEY (MODS*NTOK)        // 6912
// Q is pre-scaled by 1/sqrt(32) * log2(e) so softmax is exp2(S) directly.
#define QSC (0.17677669529663687f * 1.4426950408889634f)

#ifndef __has_builtin
#define __has_builtin(x) 0
#endif
#if __has_builtin(__builtin_amdgcn_exp2f)
#define EXP2(x) __builtin_amdgcn_exp2f(x)
#else
#define EXP2(x) __expf(0.69314718055994531f * (x))
#endif

typedef __bf16 bf16x8 __attribute__((ext_vector_type(8)));
typedef float  f32x16 __attribute__((ext_vector_type(16)));
typedef unsigned int u32x4 __attribute__((ext_vector_type(4)));

__device__ inline bf16x8 ldb8(const unsigned short* p) {
    return *reinterpret_cast<const bf16x8*>(p);
}
// V B-fragment for one 16-key window with the g(hi,j) pairing:
// elems 0-3 = keys base+4hi.., elems 4-7 = keys base+8+4hi..  (p includes +4hi)
__device__ inline bf16x8 vfrag(const unsigned short* p) {
    uint2 a = *reinterpret_cast<const uint2*>(p);
    uint2 b = *reinterpret_cast<const uint2*>(p + 8);
    u32x4 u = {a.x, a.y, b.x, b.y};
    return __builtin_bit_cast(bf16x8, u);
}
__device__ inline unsigned int pkbf(float a, float b) {
    unsigned short ua = __builtin_bit_cast(unsigned short, (__bf16)a);
    unsigned short ub = __builtin_bit_cast(unsigned short, (__bf16)b);
    return (unsigned int)ua | ((unsigned int)ub << 16);
}

// ---------------------------------------------------------------------------
// Kernel 1: LDS-tiled QKV projection (fp32 math, bf16 out).
// Block = (t,m, o-half 64, n-tile 64); 256 thr; thread = 4o x 4n register tile.
// Qb/Kb: bf16 [m][h][n][32] (Q pre-scaled by QSC).  Vt: bf16 [h][32d][key].
// ---------------------------------------------------------------------------
__global__ __launch_bounds__(256) void proj_kernel(
    const float* __restrict__ f0, const float* __restrict__ f1,
    const float* __restrict__ f2, const float* __restrict__ f3,
    const float* __restrict__ Wq, const float* __restrict__ Wk,
    const float* __restrict__ Wv,
    unsigned short* __restrict__ Qb, unsigned short* __restrict__ Kb,
    unsigned short* __restrict__ Vt)
{
    __shared__ __align__(16) float Wt[128][68];   // [c][o'] transposed, 34 KB
    __shared__ __align__(16) float fs[128][68];   // [c][n'] , 34 KB

    const int tid = threadIdx.x;
    const int bid = blockIdx.x;
    const int tm  = bid / 54;         // 0..11 = (t,m)
    const int rem = bid % 54;
    const int oh  = rem & 1;          // o-half
    const int nt  = rem >> 1;         // 0..26 n-tile
    const int t   = tm >> 2, m = tm & 3;
    const int nb  = nt * 64;

    const float* fsrc = (m == 0) ? f0 : (m == 1) ? f1 : (m == 2) ? f2 : f3;
    const float* W    = ((t == 0) ? Wq : (t == 1) ? Wk : Wv) + (size_t)m * CH * CH;

    // stage W^T tile: Wt[c][o'] = W[oh*64+o'][c]
    {
        const int o = tid & 63, c4b = tid >> 6;
        #pragma unroll
        for (int j = 0; j < 8; ++j) {
            const int c4 = c4b + 4 * j;
            float4 wv = *reinterpret_cast<const float4*>(W + (size_t)(oh * 64 + o) * CH + c4 * 4);
            Wt[c4*4+0][o] = wv.x; Wt[c4*4+1][o] = wv.y;
            Wt[c4*4+2][o] = wv.z; Wt[c4*4+3][o] = wv.w;
        }
    }
    // stage f tile: fs[c][n'] = f[c][nb+n']
    {
        const int nchunk = tid & 15, cb = tid >> 4;
        #pragma unroll
        for (int j = 0; j < 8; ++j) {
            const int c = cb + 16 * j;
            float4 v = *reinterpret_cast<const float4*>(fsrc + (size_t)c * NTOK + nb + nchunk * 4);
            *reinterpret_cast<float4*>(&fs[c][nchunk * 4]) = v;
        }
    }
    __syncthreads();

    const int o0 = (tid >> 4) * 4, nn0 = (tid & 15) * 4;
    float acc[4][4] = {};
    #pragma unroll 4
    for (int c = 0; c < CH; ++c) {
        float4 wv = *reinterpret_cast<const float4*>(&Wt[c][o0]);
        float4 fv = *reinterpret_cast<const float4*>(&fs[c][nn0]);
        acc[0][0] = fmaf(wv.x, fv.x, acc[0][0]); acc[0][1] = fmaf(wv.x, fv.y, acc[0][1]);
        acc[0][2] = fmaf(wv.x, fv.z, acc[0][2]); acc[0][3] = fmaf(wv.x, fv.w, acc[0][3]);
        acc[1][0] = fmaf(wv.y, fv.x, acc[1][0]); acc[1][1] = fmaf(wv.y, fv.y, acc[1][1]);
        acc[1][2] = fmaf(wv.y, fv.z, acc[1][2]); acc[1][3] = fmaf(wv.y, fv.w, acc[1][3]);
        acc[2][0] = fmaf(wv.z, fv.x, acc[2][0]); acc[2][1] = fmaf(wv.z, fv.y, acc[2][1]);
        acc[2][2] = fmaf(wv.z, fv.z, acc[2][2]); acc[2][3] = fmaf(wv.z, fv.w, acc[2][3]);
        acc[3][0] = fmaf(wv.w, fv.x, acc[3][0]); acc[3][1] = fmaf(wv.w, fv.y, acc[3][1]);
        acc[3][2] = fmaf(wv.w, fv.z, acc[3][2]); acc[3][3] = fmaf(wv.w, fv.w, acc[3][3]);
    }

    const int og0 = oh * 64 + o0;
    const int h = og0 >> 5, d0 = og0 & 31;
    const int ng = nb + nn0;
    if (t == 2) {
        #pragma unroll
        for (int i = 0; i < 4; ++i) {
            ushort4 pk;
            pk.x = __builtin_bit_cast(unsigned short, (__bf16)acc[i][0]);
            pk.y = __builtin_bit_cast(unsigned short, (__bf16)acc[i][1]);
            pk.z = __builtin_bit_cast(unsigned short, (__bf16)acc[i][2]);
            pk.w = __builtin_bit_cast(unsigned short, (__bf16)acc[i][3]);
            *reinterpret_cast<ushort4*>(Vt + (size_t)(h * HDIM + d0 + i) * NKEY + m * NTOK + ng) = pk;
        }
    } else {
        const float sc = (t == 0) ? QSC : 1.0f;
        unsigned short* base = ((t == 0) ? Qb : Kb)
            + (((size_t)(m * NHD + h)) * NTOK + ng) * HDIM + d0;
        #pragma unroll
        for (int j = 0; j < 4; ++j) {
            unsigned short* row = base + (size_t)j * HDIM;
            *reinterpret_cast<unsigned int*>(row)     = pkbf(acc[0][j] * sc, acc[1][j] * sc);
            *reinterpret_cast<unsigned int*>(row + 2) = pkbf(acc[2][j] * sc, acc[3][j] * sc);
        }
    }
}

// ---------------------------------------------------------------------------
// Kernel 2: MFMA cross-modal attention. 864 blocks x 512 thr (8 waves).
// Block = (head h, 32-query tile). wave w: km = w>>1 (key modality),
// kseg = w&1 (864-key half) -> 27 iters x 32 keys, register K/V prefetch.
// Swapped QK^T (verified R4): lane (q=l&31, hi=l>>5) holds P for keys
// k(r,hi) = (r&3)+8*(r>>2)+4hi; PV uses the pairing g(hi,j)=(j&3)+4hi+8(j>>2)
// so P packs in-lane (no cross-lane movement) and V loads the matching
// interleave. Max-free softmax: 8 k-split partials just add.
// ---------------------------------------------------------------------------
__global__ __launch_bounds__(512) void attn_kernel(
    const unsigned short* __restrict__ Qb, const unsigned short* __restrict__ Kb,
    const unsigned short* __restrict__ Vt, float* __restrict__ out4)
{
    __shared__ float accL[8][32][32];   // [ksplit][q][d] 32 KB
    __shared__ float sL[8][2][32];      // [ksplit][hi][q] 2 KB

    const int tid  = threadIdx.x;
    const int lane = tid & 63;
    const int w    = tid >> 6;
    const int km   = w >> 1;
    const int kseg = w & 1;
    const int l31  = lane & 31;
    const int hi   = lane >> 5;

    const int bid = blockIdx.x;
    const int s8  = bid & 7;                       // XCD slot
    const int h   = s8 >> 1;                       // 2 XCDs per head
    const int qtile = (s8 & 1) * 108 + (bid >> 3); // 0..215
    const int qg0 = qtile * 32;
    const int im  = qg0 / NTOK;
    const int n0  = qg0 % NTOK;

    // Q fragments (pre-scaled by QSC at proj time)
    const unsigned short* qp = Qb + (((size_t)(im * NHD + h)) * NTOK + n0 + l31) * HDIM + hi * 8;
    const bf16x8 qf0 = ldb8(qp);
    const bf16x8 qf1 = ldb8(qp + 16);

    const unsigned short* kp = Kb
        + (((size_t)(km * NHD + h)) * NTOK + kseg * 864 + l31) * HDIM + hi * 8;
    const unsigned short* vb = Vt
        + ((size_t)(h * HDIM + l31)) * NKEY + km * NTOK + kseg * 864 + 4 * hi;

    f32x16 o_acc;
    #pragma unroll
    for (int r = 0; r < 16; ++r) o_acc[r] = 0.f;
    float s_part = 0.f;

    bf16x8 kc0 = ldb8(kp), kc1 = ldb8(kp + 16);
    bf16x8 vc0 = vfrag(vb), vc1 = vfrag(vb + 16);

    for (int it = 0; it < 27; ++it) {
        // prefetch next 32-key tile (last-iter overrun stays inside d_ws)
        const unsigned short* kpn = kp + 32 * HDIM;
        const unsigned short* vbn = vb + 32;
        bf16x8 kn0 = ldb8(kpn), kn1 = ldb8(kpn + 16);
        bf16x8 vn0 = vfrag(vbn), vn1 = vfrag(vbn + 16);

        // QK^T: S^T[32k][32q], K=32 via 2 chained MFMAs
        f32x16 c0;
        #pragma unroll
        for (int r = 0; r < 16; ++r) c0[r] = 0.f;
        c0 = __builtin_amdgcn_mfma_f32_32x32x16_bf16(kc0, qf0, c0, 0, 0, 0);
        c0 = __builtin_amdgcn_mfma_f32_32x32x16_bf16(kc1, qf1, c0, 0, 0, 0);

        // softmax numerators: exp2 (scale folded into Q), max-free
        float e[16];
        #pragma unroll
        for (int r = 0; r < 16; ++r) { e[r] = EXP2(c0[r]); s_part += e[r]; }

        // pack P (plain casts -> v_cvt_pk_bf16_f32), in-lane pairing
        bf16x8 pa0, pa1;
        #pragma unroll
        for (int j = 0; j < 8; ++j) { pa0[j] = (__bf16)e[j]; pa1[j] = (__bf16)e[8 + j]; }

        // PV: accumulate O[32q][32d]
        o_acc = __builtin_amdgcn_mfma_f32_32x32x16_bf16(pa0, vc0, o_acc, 0, 0, 0);
        o_acc = __builtin_amdgcn_mfma_f32_32x32x16_bf16(pa1, vc1, o_acc, 0, 0, 0);

        kc0 = kn0; kc1 = kn1; vc0 = vn0; vc1 = vn1;
        kp = kpn; vb = vbn;
    }

    // spill per-split partials
    #pragma unroll
    for (int r = 0; r < 16; ++r) {
        const int qrow = (r & 3) + 8 * (r >> 2) + 4 * hi;
        accL[w][qrow][l31] = o_acc[r];
    }
    sL[w][hi][l31] = s_part;
    __syncthreads();

    // combine 8 k-splits, normalize, write out4[c][n][im]
    {
        const int q  = tid >> 4;          // 0..31
        const int dd = (tid & 15) * 2;    // 0..30
        float st = 0.f;
        #pragma unroll
        for (int s = 0; s < 8; ++s) st += sL[s][0][q] + sL[s][1][q];
        const float r = 1.0f / st;
        float a0 = 0.f, a1 = 0.f;
        #pragma unroll
        for (int s = 0; s < 8; ++s) { a0 += accL[s][q][dd]; a1 += accL[s][q][dd + 1]; }
        const int cn = n0 + q;
        const size_t c = (size_t)(h * HDIM + dd);
        out4[(c * NTOK + cn) * MODS + im]       = a0 * r;
        out4[((c + 1) * NTOK + cn) * MODS + im] = a1 * r;
    }
}

// ---------------------------------------------------------------------------
// Kernel 3: modality-sum  fused[c][n] = sum_i out4[c][n][i]
// ---------------------------------------------------------------------------
__global__ __launch_bounds__(256) void sum4_kernel(
    const float* __restrict__ out4, float* __restrict__ fused)
{
    const int idx = blockIdx.x * 256 + threadIdx.x;   // c*NTOK+n
    float4 v = *reinterpret_cast<const float4*>(out4 + (size_t)idx * 4);
    fused[idx] = (v.x + v.y) + (v.z + v.w);
}

// ---------------------------------------------------------------------------
// Kernel 4: out-proj (Wout @ fused) + BatchNorm(eval) + ReLU
// ---------------------------------------------------------------------------
__global__ __launch_bounds__(256) void outproj_kernel(
    const float* __restrict__ fused, const float* __restrict__ Wout,
    const float* __restrict__ gamma, const float* __restrict__ beta,
    const float* __restrict__ mean,  const float* __restrict__ var,
    float* __restrict__ out)
{
    int idx = blockIdx.x * blockDim.x + threadIdx.x;
    if (idx >= CH * NG) return;
    int n4 = idx % NG;
    int o  = idx / NG;
    const float* W     = Wout + (size_t)o * CH;
    const float* fbase = fused + n4 * 4;
    float a0 = 0.f, a1 = 0.f, a2 = 0.f, a3 = 0.f;
    #pragma unroll 8
    for (int c = 0; c < CH; c += 4) {
        float4 w4 = *reinterpret_cast<const float4*>(W + c);
        float4 r0 = *reinterpret_cast<const float4*>(fbase + (size_t)(c + 0) * NTOK);
        float4 r1 = *reinterpret_cast<const float4*>(fbase + (size_t)(c + 1) * NTOK);
        float4 r2 = *reinterpret_cast<const float4*>(fbase + (size_t)(c + 2) * NTOK);
        float4 r3 = *reinterpret_cast<const float4*>(fbase + (size_t)(c + 3) * NTOK);
        a0 = fmaf(w4.x, r0.x, a0); a0 = fmaf(w4.y, r1.x, a0); a0 = fmaf(w4.z, r2.x, a0); a0 = fmaf(w4.w, r3.x, a0);
        a1 = fmaf(w4.x, r0.y, a1); a1 = fmaf(w4.y, r1.y, a1); a1 = fmaf(w4.z, r2.y, a1); a1 = fmaf(w4.w, r3.y, a1);
        a2 = fmaf(w4.x, r0.z, a2); a2 = fmaf(w4.y, r1.z, a2); a2 = fmaf(w4.z, r2.z, a2); a2 = fmaf(w4.w, r3.z, a2);
        a3 = fmaf(w4.x, r0.w, a3); a3 = fmaf(w4.y, r1.w, a3); a3 = fmaf(w4.z, r2.w, a3); a3 = fmaf(w4.w, r3.w, a3);
    }
    float inv = gamma[o] * rsqrtf(var[o] + 1e-5f);
    float sh  = fmaf(-mean[o], inv, beta[o]);
    float4 y;
    y.x = fmaxf(fmaf(a0, inv, sh), 0.f);
    y.y = fmaxf(fmaf(a1, inv, sh), 0.f);
    y.z = fmaxf(fmaf(a2, inv, sh), 0.f);
    y.w = fmaxf(fmaf(a3, inv, sh), 0.f);
    *reinterpret_cast<float4*>(out + (size_t)o * NTOK + n4 * 4) = y;
}

// ---------------------------------------------------------------------------
extern "C" void kernel_launch(void* const* d_in, const int* in_sizes, int n_in,
                              void* d_out, int out_size, void* d_ws, size_t ws_size,
                              hipStream_t stream)
{
    const float* f0    = (const float*)d_in[0];
    const float* f1    = (const float*)d_in[1];
    const float* f2    = (const float*)d_in[2];
    const float* f3    = (const float*)d_in[3];
    const float* Wq    = (const float*)d_in[4];
    const float* Wk    = (const float*)d_in[5];
    const float* Wv    = (const float*)d_in[6];
    const float* Wout  = (const float*)d_in[7];
    const float* gamma = (const float*)d_in[8];
    const float* beta  = (const float*)d_in[9];
    const float* mean  = (const float*)d_in[10];
    const float* var   = (const float*)d_in[11];
    float* out = (float*)d_out;

    const size_t QKV = (size_t)MODS * NHD * NTOK * HDIM;   // 884736 elems
    unsigned short* Qb = (unsigned short*)d_ws;
    unsigned short* Kb = Qb + QKV;
    unsigned short* Vt = Kb + QKV;
    float* out4  = (float*)(Vt + QKV);      // [CH][NTOK][MODS] f32
    float* fused = out4 + QKV;              // [CH][NTOK] f32

    proj_kernel<<<648, 256, 0, stream>>>(f0, f1, f2, f3, Wq, Wk, Wv, Qb, Kb, Vt);
    attn_kernel<<<864, 512, 0, stream>>>(Qb, Kb, Vt, out4);
    sum4_kernel<<<(CH * NTOK) / 256, 256, 0, stream>>>(out4, fused);
    outproj_kernel<<<(CH * NG) / 256, 256, 0, stream>>>(
        fused, Wout, gamma, beta, mean, var, out);
}

// Round 6
// 98.027 us; speedup vs baseline: 63.5299x; 1.7591x over previous
//
#include <hip/hip_runtime.h>

#define MODS 4
#define CH   128
#define NHD  4
#define HDIM 32
#define NTOK 1728
#define NG   (NTOK/4)
#define NKEY (MODS*NTOK)        // 6912
#define NT   27                 // 64-key tiles per 1728-key stream
// Q is pre-scaled by 1/sqrt(32) * log2(e) so softmax is exp2(S) directly.
#define QSC (0.17677669529663687f * 1.4426950408889634f)

#ifndef __has_builtin
#define __has_builtin(x) 0
#endif
#if __has_builtin(__builtin_amdgcn_exp2f)
#define EXP2(x) __builtin_amdgcn_exp2f(x)
#else
#define EXP2(x) __expf(0.69314718055994531f * (x))
#endif

typedef __bf16 bf16x8 __attribute__((ext_vector_type(8)));
typedef float  f32x16 __attribute__((ext_vector_type(16)));
typedef unsigned int u32x4 __attribute__((ext_vector_type(4)));

__device__ inline bf16x8 ldb8(const unsigned short* p) {
    return *reinterpret_cast<const bf16x8*>(p);
}
__device__ inline unsigned int pkbf(float a, float b) {
    unsigned short ua = __builtin_bit_cast(unsigned short, (__bf16)a);
    unsigned short ub = __builtin_bit_cast(unsigned short, (__bf16)b);
    return (unsigned int)ua | ((unsigned int)ub << 16);
}
// async global->LDS, 16B per lane; LDS dest = uniform base + lane*16
__device__ inline void glds16(const unsigned short* g, unsigned short* l) {
    __builtin_amdgcn_global_load_lds(
        (const __attribute__((address_space(1))) unsigned int*)(g),
        (__attribute__((address_space(3))) unsigned int*)(l), 16, 0, 0);
}

// ---------------------------------------------------------------------------
// Kernel 1: LDS-tiled QKV projection (fp32 math, bf16 out).
// Qb/Kb: bf16 [m][h][n][32] (Q pre-scaled by QSC).  Vt: bf16 [h][32d][key].
// ---------------------------------------------------------------------------
__global__ __launch_bounds__(256) void proj_kernel(
    const float* __restrict__ f0, const float* __restrict__ f1,
    const float* __restrict__ f2, const float* __restrict__ f3,
    const float* __restrict__ Wq, const float* __restrict__ Wk,
    const float* __restrict__ Wv,
    unsigned short* __restrict__ Qb, unsigned short* __restrict__ Kb,
    unsigned short* __restrict__ Vt)
{
    __shared__ __align__(16) float Wt[128][68];
    __shared__ __align__(16) float fs[128][68];

    const int tid = threadIdx.x;
    const int bid = blockIdx.x;
    const int tm  = bid / 54;
    const int rem = bid % 54;
    const int oh  = rem & 1;
    const int nt  = rem >> 1;
    const int t   = tm >> 2, m = tm & 3;
    const int nb  = nt * 64;

    const float* fsrc = (m == 0) ? f0 : (m == 1) ? f1 : (m == 2) ? f2 : f3;
    const float* W    = ((t == 0) ? Wq : (t == 1) ? Wk : Wv) + (size_t)m * CH * CH;

    {
        const int o = tid & 63, c4b = tid >> 6;
        #pragma unroll
        for (int j = 0; j < 8; ++j) {
            const int c4 = c4b + 4 * j;
            float4 wv = *reinterpret_cast<const float4*>(W + (size_t)(oh * 64 + o) * CH + c4 * 4);
            Wt[c4*4+0][o] = wv.x; Wt[c4*4+1][o] = wv.y;
            Wt[c4*4+2][o] = wv.z; Wt[c4*4+3][o] = wv.w;
        }
    }
    {
        const int nchunk = tid & 15, cb = tid >> 4;
        #pragma unroll
        for (int j = 0; j < 8; ++j) {
            const int c = cb + 16 * j;
            float4 v = *reinterpret_cast<const float4*>(fsrc + (size_t)c * NTOK + nb + nchunk * 4);
            *reinterpret_cast<float4*>(&fs[c][nchunk * 4]) = v;
        }
    }
    __syncthreads();

    const int o0 = (tid >> 4) * 4, nn0 = (tid & 15) * 4;
    float acc[4][4] = {};
    #pragma unroll 4
    for (int c = 0; c < CH; ++c) {
        float4 wv = *reinterpret_cast<const float4*>(&Wt[c][o0]);
        float4 fv = *reinterpret_cast<const float4*>(&fs[c][nn0]);
        acc[0][0] = fmaf(wv.x, fv.x, acc[0][0]); acc[0][1] = fmaf(wv.x, fv.y, acc[0][1]);
        acc[0][2] = fmaf(wv.x, fv.z, acc[0][2]); acc[0][3] = fmaf(wv.x, fv.w, acc[0][3]);
        acc[1][0] = fmaf(wv.y, fv.x, acc[1][0]); acc[1][1] = fmaf(wv.y, fv.y, acc[1][1]);
        acc[1][2] = fmaf(wv.y, fv.z, acc[1][2]); acc[1][3] = fmaf(wv.y, fv.w, acc[1][3]);
        acc[2][0] = fmaf(wv.z, fv.x, acc[2][0]); acc[2][1] = fmaf(wv.z, fv.y, acc[2][1]);
        acc[2][2] = fmaf(wv.z, fv.z, acc[2][2]); acc[2][3] = fmaf(wv.z, fv.w, acc[2][3]);
        acc[3][0] = fmaf(wv.w, fv.x, acc[3][0]); acc[3][1] = fmaf(wv.w, fv.y, acc[3][1]);
        acc[3][2] = fmaf(wv.w, fv.z, acc[3][2]); acc[3][3] = fmaf(wv.w, fv.w, acc[3][3]);
    }

    const int og0 = oh * 64 + o0;
    const int h = og0 >> 5, d0 = og0 & 31;
    const int ng = nb + nn0;
    if (t == 2) {
        #pragma unroll
        for (int i = 0; i < 4; ++i) {
            ushort4 pk;
            pk.x = __builtin_bit_cast(unsigned short, (__bf16)acc[i][0]);
            pk.y = __builtin_bit_cast(unsigned short, (__bf16)acc[i][1]);
            pk.z = __builtin_bit_cast(unsigned short, (__bf16)acc[i][2]);
            pk.w = __builtin_bit_cast(unsigned short, (__bf16)acc[i][3]);
            *reinterpret_cast<ushort4*>(Vt + (size_t)(h * HDIM + d0 + i) * NKEY + m * NTOK + ng) = pk;
        }
    } else {
        const float sc = (t == 0) ? QSC : 1.0f;
        unsigned short* base = ((t == 0) ? Qb : Kb)
            + (((size_t)(m * NHD + h)) * NTOK + ng) * HDIM + d0;
        #pragma unroll
        for (int j = 0; j < 4; ++j) {
            unsigned short* row = base + (size_t)j * HDIM;
            *reinterpret_cast<unsigned int*>(row)     = pkbf(acc[0][j] * sc, acc[1][j] * sc);
            *reinterpret_cast<unsigned int*>(row + 2) = pkbf(acc[2][j] * sc, acc[3][j] * sc);
        }
    }
}

// ---------------------------------------------------------------------------
// Kernel 2: MFMA cross-modal attention, LDS-staged K/V shared by all waves.
// 432 blocks x 512 thr. bid -> slot=bid&7 (XCD): h=slot>>1, ko=slot&1 (outer
// key half); qb=bid>>3. Wave w: qslot=w&3 (32-q tile), ks=w>>2 (inner key
// stream => modality km=2ko+ks). Per 64-key tile: K(4KB)+V(4KB) staged via
// global_load_lds (chunk-XOR swizzle on SOURCE addr, involution on ds_read;
// bank-uniform by construction), double-buffered, 1 barrier/tile.
// MFMA fragments identical to verified R4/R5 pairing. Max-free exp2 softmax.
// Raw acc/s per (ko) written to accR/sR; normalize kernel combines.
// ---------------------------------------------------------------------------
__global__ __launch_bounds__(512) void attn_kernel(
    const unsigned short* __restrict__ Qb, const unsigned short* __restrict__ Kb,
    const unsigned short* __restrict__ Vt,
    float* __restrict__ accR, float* __restrict__ sR)
{
    __shared__ __align__(16) unsigned short smAll[2][2][2][2048]; // [ks][buf][K/V] 32 KB
    __shared__ __align__(16) float sf[4][2][2][32];               // 2 KB

    const int tid  = threadIdx.x;
    const int lane = tid & 63;
    const int w    = tid >> 6;
    const int qslot = w & 3;
    const int ks    = w >> 2;
    const int l31  = lane & 31;
    const int hi   = lane >> 5;

    const int bid  = blockIdx.x;
    const int slot = bid & 7;
    const int h    = slot >> 1;
    const int ko   = slot & 1;
    const int qb   = bid >> 3;             // 0..53
    const int qtile = qb * 4 + qslot;      // 0..215
    const int qg0  = qtile * 32;
    const int im   = qg0 / NTOK;
    const int n0   = qg0 % NTOK;
    const int km   = ko * 2 + ks;          // key modality of this stream

    // Q fragments (pre-scaled by QSC)
    const unsigned short* qp = Qb + (((size_t)(im * NHD + h)) * NTOK + n0 + l31) * HDIM + hi * 8;
    const bf16x8 qf0 = ldb8(qp);
    const bf16x8 qf1 = ldb8(qp + 16);

    unsigned short* sm = &smAll[ks][0][0][0];   // 8192 shorts per stream

    // --- staging source pointers (per lane, inverse-swizzled chunks) ---
    const int rK = qslot * 16 + (lane >> 2);         // K tile row (key)
    const int cK = (lane & 3) ^ (rK & 3);            // global 16B chunk
    const unsigned short* gK = Kb + (((size_t)(km * NHD + h)) * NTOK + rK) * HDIM + cK * 8;
    const int dV = qslot * 8 + (lane >> 3);          // V tile row (d)
    const int cV = (lane & 7) ^ (dV & 7);
    const unsigned short* gV = Vt + ((size_t)(h * HDIM + dV)) * NKEY + km * NTOK + cV * 8;

    // --- LDS read offsets (shorts), swizzle involution applied ---
    const int kA = l31 * 32 + (((hi)     ^ (l31 & 3)) << 3);
    const int kB = l31 * 32 + (((2 + hi) ^ (l31 & 3)) << 3);

    f32x16 o_acc;
    #pragma unroll
    for (int r = 0; r < 16; ++r) o_acc[r] = 0.f;
    float s_part = 0.f;
    int buf = 0;

    // prologue: stage tile 0
    glds16(gK, sm + qslot * 512);
    glds16(gV, sm + 2048 + qslot * 512);
    gK += 64 * HDIM; gV += 64;
    __syncthreads();

    for (int t = 0; t < NT; ++t) {
        if (t + 1 < NT) {
            unsigned short* dst = sm + (buf ^ 1) * 4096;
            glds16(gK, dst + qslot * 512);
            glds16(gV, dst + 2048 + qslot * 512);
            gK += 64 * HDIM; gV += 64;
        }
        const unsigned short* Kl = sm + buf * 4096;
        const unsigned short* Vl = Kl + 2048;

        #pragma unroll
        for (int st = 0; st < 2; ++st) {
            bf16x8 k0 = ldb8(Kl + st * 1024 + kA);
            bf16x8 k1 = ldb8(Kl + st * 1024 + kB);
            f32x16 c;
            #pragma unroll
            for (int r = 0; r < 16; ++r) c[r] = 0.f;
            c = __builtin_amdgcn_mfma_f32_32x32x16_bf16(k0, qf0, c, 0, 0, 0);
            c = __builtin_amdgcn_mfma_f32_32x32x16_bf16(k1, qf1, c, 0, 0, 0);

            float e[16];
            #pragma unroll
            for (int r = 0; r < 16; ++r) { e[r] = EXP2(c[r]); s_part += e[r]; }
            bf16x8 pa0, pa1;
            #pragma unroll
            for (int j = 0; j < 8; ++j) { pa0[j] = (__bf16)e[j]; pa1[j] = (__bf16)e[8 + j]; }

            // V windows 2st, 2st+1 (granule pairing identical to R4/R5)
            const int nw0 = 2 * st, nw1 = 2 * st + 1;
            const int a00 = l31 * 64 + (((2 * nw0)     ^ (l31 & 7)) << 3) + hi * 4;
            const int a01 = l31 * 64 + (((2 * nw0 + 1) ^ (l31 & 7)) << 3) + hi * 4;
            const int a10 = l31 * 64 + (((2 * nw1)     ^ (l31 & 7)) << 3) + hi * 4;
            const int a11 = l31 * 64 + (((2 * nw1 + 1) ^ (l31 & 7)) << 3) + hi * 4;
            uint2 x0 = *reinterpret_cast<const uint2*>(Vl + a00);
            uint2 y0 = *reinterpret_cast<const uint2*>(Vl + a01);
            uint2 x1 = *reinterpret_cast<const uint2*>(Vl + a10);
            uint2 y1 = *reinterpret_cast<const uint2*>(Vl + a11);
            u32x4 u0 = {x0.x, x0.y, y0.x, y0.y};
            u32x4 u1 = {x1.x, x1.y, y1.x, y1.y};
            bf16x8 v0 = __builtin_bit_cast(bf16x8, u0);
            bf16x8 v1 = __builtin_bit_cast(bf16x8, u1);

            o_acc = __builtin_amdgcn_mfma_f32_32x32x16_bf16(pa0, v0, o_acc, 0, 0, 0);
            o_acc = __builtin_amdgcn_mfma_f32_32x32x16_bf16(pa1, v1, o_acc, 0, 0, 0);
        }
        __syncthreads();
        buf ^= 1;
    }

    // --- combine the 2 inner key streams, write raw partials for (ko) ---
    float* accf = (float*)&smAll[0][0][0][0];   // 4*32*32 f32 = 16 KB (reuse)
    if (ks == 1) {
        #pragma unroll
        for (int r = 0; r < 16; ++r) {
            const int qrow = (r & 3) + 8 * (r >> 2) + 4 * hi;
            accf[((size_t)qslot * 32 + qrow) * 32 + l31] = o_acc[r];
        }
    }
    sf[qslot][ks][hi][l31] = s_part;
    __syncthreads();
    if (ks == 0) {
        float* base = accR + (((size_t)(ko * NHD + h) * NKEY) + qtile * 32) * 32;
        #pragma unroll
        for (int r = 0; r < 16; ++r) {
            const int qrow = (r & 3) + 8 * (r >> 2) + 4 * hi;
            base[(size_t)qrow * 32 + l31] =
                o_acc[r] + accf[((size_t)qslot * 32 + qrow) * 32 + l31];
        }
        if (hi == 0) {
            float st = (sf[qslot][0][0][l31] + sf[qslot][0][1][l31])
                     + (sf[qslot][1][0][l31] + sf[qslot][1][1][l31]);
            sR[(size_t)(ko * NHD + h) * NKEY + qtile * 32 + l31] = st;
        }
    }
}

// ---------------------------------------------------------------------------
// Kernel 3: combine outer key halves + normalize + modality-sum.
// thread = (h, n): fused[(h*32+d)][n] = sum_im (acc0+acc1)[h][im*1728+n][d]/si
// ---------------------------------------------------------------------------
__global__ __launch_bounds__(256) void norm_kernel(
    const float* __restrict__ accR, const float* __restrict__ sR,
    float* __restrict__ fused)
{
    const int idx = blockIdx.x * 256 + threadIdx.x;   // 0..6911
    const int h = idx / NTOK, n = idx % NTOK;
    float4 o[8];
    #pragma unroll
    for (int j = 0; j < 8; ++j) o[j] = make_float4(0.f, 0.f, 0.f, 0.f);
    #pragma unroll
    for (int imq = 0; imq < MODS; ++imq) {
        const size_t q = (size_t)imq * NTOK + n;
        const float si = sR[(size_t)(0 * NHD + h) * NKEY + q]
                       + sR[(size_t)(1 * NHD + h) * NKEY + q];
        const float ri = 1.0f / si;
        const float* a0 = accR + ((size_t)(0 * NHD + h) * NKEY + q) * 32;
        const float* a1 = accR + ((size_t)(1 * NHD + h) * NKEY + q) * 32;
        #pragma unroll
        for (int j = 0; j < 8; ++j) {
            float4 x = *reinterpret_cast<const float4*>(a0 + 4 * j);
            float4 y = *reinterpret_cast<const float4*>(a1 + 4 * j);
            o[j].x = fmaf(x.x + y.x, ri, o[j].x);
            o[j].y = fmaf(x.y + y.y, ri, o[j].y);
            o[j].z = fmaf(x.z + y.z, ri, o[j].z);
            o[j].w = fmaf(x.w + y.w, ri, o[j].w);
        }
    }
    #pragma unroll
    for (int j = 0; j < 8; ++j) {
        fused[(size_t)(h * HDIM + 4 * j + 0) * NTOK + n] = o[j].x;
        fused[(size_t)(h * HDIM + 4 * j + 1) * NTOK + n] = o[j].y;
        fused[(size_t)(h * HDIM + 4 * j + 2) * NTOK + n] = o[j].z;
        fused[(size_t)(h * HDIM + 4 * j + 3) * NTOK + n] = o[j].w;
    }
}

// ---------------------------------------------------------------------------
// Kernel 4: out-proj (Wout @ fused) + BatchNorm(eval) + ReLU
// ---------------------------------------------------------------------------
__global__ __launch_bounds__(256) void outproj_kernel(
    const float* __restrict__ fused, const float* __restrict__ Wout,
    const float* __restrict__ gamma, const float* __restrict__ beta,
    const float* __restrict__ mean,  const float* __restrict__ var,
    float* __restrict__ out)
{
    int idx = blockIdx.x * blockDim.x + threadIdx.x;
    if (idx >= CH * NG) return;
    int n4 = idx % NG;
    int o  = idx / NG;
    const float* W     = Wout + (size_t)o * CH;
    const float* fbase = fused + n4 * 4;
    float a0 = 0.f, a1 = 0.f, a2 = 0.f, a3 = 0.f;
    #pragma unroll 8
    for (int c = 0; c < CH; c += 4) {
        float4 w4 = *reinterpret_cast<const float4*>(W + c);
        float4 r0 = *reinterpret_cast<const float4*>(fbase + (size_t)(c + 0) * NTOK);
        float4 r1 = *reinterpret_cast<const float4*>(fbase + (size_t)(c + 1) * NTOK);
        float4 r2 = *reinterpret_cast<const float4*>(fbase + (size_t)(c + 2) * NTOK);
        float4 r3 = *reinterpret_cast<const float4*>(fbase + (size_t)(c + 3) * NTOK);
        a0 = fmaf(w4.x, r0.x, a0); a0 = fmaf(w4.y, r1.x, a0); a0 = fmaf(w4.z, r2.x, a0); a0 = fmaf(w4.w, r3.x, a0);
        a1 = fmaf(w4.x, r0.y, a1); a1 = fmaf(w4.y, r1.y, a1); a1 = fmaf(w4.z, r2.y, a1); a1 = fmaf(w4.w, r3.y, a1);
        a2 = fmaf(w4.x, r0.z, a2); a2 = fmaf(w4.y, r1.z, a2); a2 = fmaf(w4.z, r2.z, a2); a2 = fmaf(w4.w, r3.z, a2);
        a3 = fmaf(w4.x, r0.w, a3); a3 = fmaf(w4.y, r1.w, a3); a3 = fmaf(w4.z, r2.w, a3); a3 = fmaf(w4.w, r3.w, a3);
    }
    float inv = gamma[o] * rsqrtf(var[o] + 1e-5f);
    float sh  = fmaf(-mean[o], inv, beta[o]);
    float4 y;
    y.x = fmaxf(fmaf(a0, inv, sh), 0.f);
    y.y = fmaxf(fmaf(a1, inv, sh), 0.f);
    y.z = fmaxf(fmaf(a2, inv, sh), 0.f);
    y.w = fmaxf(fmaf(a3, inv, sh), 0.f);
    *reinterpret_cast<float4*>(out + (size_t)o * NTOK + n4 * 4) = y;
}

// ---------------------------------------------------------------------------
extern "C" void kernel_launch(void* const* d_in, const int* in_sizes, int n_in,
                              void* d_out, int out_size, void* d_ws, size_t ws_size,
                              hipStream_t stream)
{
    const float* f0    = (const float*)d_in[0];
    const float* f1    = (const float*)d_in[1];
    const float* f2    = (const float*)d_in[2];
    const float* f3    = (const float*)d_in[3];
    const float* Wq    = (const float*)d_in[4];
    const float* Wk    = (const float*)d_in[5];
    const float* Wv    = (const float*)d_in[6];
    const float* Wout  = (const float*)d_in[7];
    const float* gamma = (const float*)d_in[8];
    const float* beta  = (const float*)d_in[9];
    const float* mean  = (const float*)d_in[10];
    const float* var   = (const float*)d_in[11];
    float* out = (float*)d_out;

    const size_t QKV = (size_t)MODS * NHD * NTOK * HDIM;   // 884736 elems
    unsigned short* Qb = (unsigned short*)d_ws;
    unsigned short* Kb = Qb + QKV;
    unsigned short* Vt = Kb + QKV;
    float* accR = (float*)(Vt + QKV);          // [2 ko][4 h][6912 q][32 d] f32
    float* sR   = accR + (size_t)2 * NHD * NKEY * HDIM;  // [2][4][6912]
    float* fused = sR + (size_t)2 * NHD * NKEY;          // [CH][NTOK]

    proj_kernel<<<648, 256, 0, stream>>>(f0, f1, f2, f3, Wq, Wk, Wv, Qb, Kb, Vt);
    attn_kernel<<<432, 512, 0, stream>>>(Qb, Kb, Vt, accR, sR);
    norm_kernel<<<(NHD * NTOK) / 256, 256, 0, stream>>>(accR, sR, fused);
    outproj_kernel<<<(CH * NG) / 256, 256, 0, stream>>>(
        fused, Wout, gamma, beta, mean, var, out);
}

// Round 7
// 75.915 us; speedup vs baseline: 82.0343x; 1.2913x over previous
//
#include <hip/hip_runtime.h>

#define MODS 4
#define CH   128
#define NHD  4
#define HDIM 32
#define NTOK 1728
#define NG   (NTOK/4)
#define NKEY (MODS*NTOK)        // 6912
#define NT   27                 // 64-key tiles per 1728-key stream
// Q is pre-scaled by 1/sqrt(32) * log2(e) so softmax is exp2(S) directly.
#define QSC (0.17677669529663687f * 1.4426950408889634f)

#ifndef __has_builtin
#define __has_builtin(x) 0
#endif
#if __has_builtin(__builtin_amdgcn_exp2f)
#define EXP2(x) __builtin_amdgcn_exp2f(x)
#else
#define EXP2(x) __expf(0.69314718055994531f * (x))
#endif

typedef __bf16 bf16x8 __attribute__((ext_vector_type(8)));
typedef float  f32x16 __attribute__((ext_vector_type(16)));
typedef unsigned int u32x4 __attribute__((ext_vector_type(4)));

__device__ inline bf16x8 ldb8(const unsigned short* p) {
    return *reinterpret_cast<const bf16x8*>(p);
}
__device__ inline unsigned int pkbf(float a, float b) {
    unsigned short ua = __builtin_bit_cast(unsigned short, (__bf16)a);
    unsigned short ub = __builtin_bit_cast(unsigned short, (__bf16)b);
    return (unsigned int)ua | ((unsigned int)ub << 16);
}
// async global->LDS, 16B per lane; LDS dest = uniform base + lane*16
__device__ inline void glds16(const unsigned short* g, unsigned short* l) {
    __builtin_amdgcn_global_load_lds(
        (const __attribute__((address_space(1))) unsigned int*)(g),
        (__attribute__((address_space(3))) unsigned int*)(l), 16, 0, 0);
}

// ---------------------------------------------------------------------------
// Kernel 1: LDS-tiled QKV projection (fp32 math, bf16 out), c-split in 2
// halves for 34 KB LDS (4 blocks/CU).
// Qb/Kb: bf16 [m][h][n][32] (Q pre-scaled by QSC).
// V2: bf16 [h][32d][key], keys fragment-ordered per 16-window:
//     4-key group at offset {0,4,8,12} stored at position {0,8,4,12}.
// ---------------------------------------------------------------------------
__global__ __launch_bounds__(256) void proj_kernel(
    const float* __restrict__ f0, const float* __restrict__ f1,
    const float* __restrict__ f2, const float* __restrict__ f3,
    const float* __restrict__ Wq, const float* __restrict__ Wk,
    const float* __restrict__ Wv,
    unsigned short* __restrict__ Qb, unsigned short* __restrict__ Kb,
    unsigned short* __restrict__ V2)
{
    __shared__ __align__(16) float Wt[64][68];   // 17 KB
    __shared__ __align__(16) float fs[64][68];   // 17 KB

    const int tid = threadIdx.x;
    const int bid = blockIdx.x;
    const int tm  = bid / 54;
    const int rem = bid % 54;
    const int oh  = rem & 1;
    const int nt  = rem >> 1;
    const int t   = tm >> 2, m = tm & 3;
    const int nb  = nt * 64;

    const float* fsrc = (m == 0) ? f0 : (m == 1) ? f1 : (m == 2) ? f2 : f3;
    const float* W    = ((t == 0) ? Wq : (t == 1) ? Wk : Wv) + (size_t)m * CH * CH;

    const int o0 = (tid >> 4) * 4, nn0 = (tid & 15) * 4;
    float acc[4][4] = {};

    for (int ch = 0; ch < 2; ++ch) {
        if (ch) __syncthreads();
        // stage W^T half: Wt[c'][o'] = W[oh*64+o'][ch*64+c']
        {
            const int o = tid & 63, c4b = tid >> 6;
            #pragma unroll
            for (int j = 0; j < 4; ++j) {
                const int c4 = c4b + 4 * j;
                float4 wv = *reinterpret_cast<const float4*>(
                    W + (size_t)(oh * 64 + o) * CH + ch * 64 + c4 * 4);
                Wt[c4*4+0][o] = wv.x; Wt[c4*4+1][o] = wv.y;
                Wt[c4*4+2][o] = wv.z; Wt[c4*4+3][o] = wv.w;
            }
        }
        // stage f half: fs[c'][n'] = f[ch*64+c'][nb+n']
        {
            const int nchunk = tid & 15, cb = tid >> 4;
            #pragma unroll
            for (int j = 0; j < 4; ++j) {
                const int c = cb + 16 * j;
                float4 v = *reinterpret_cast<const float4*>(
                    fsrc + (size_t)(ch * 64 + c) * NTOK + nb + nchunk * 4);
                *reinterpret_cast<float4*>(&fs[c][nchunk * 4]) = v;
            }
        }
        __syncthreads();
        #pragma unroll 4
        for (int c = 0; c < 64; ++c) {
            float4 wv = *reinterpret_cast<const float4*>(&Wt[c][o0]);
            float4 fv = *reinterpret_cast<const float4*>(&fs[c][nn0]);
            acc[0][0] = fmaf(wv.x, fv.x, acc[0][0]); acc[0][1] = fmaf(wv.x, fv.y, acc[0][1]);
            acc[0][2] = fmaf(wv.x, fv.z, acc[0][2]); acc[0][3] = fmaf(wv.x, fv.w, acc[0][3]);
            acc[1][0] = fmaf(wv.y, fv.x, acc[1][0]); acc[1][1] = fmaf(wv.y, fv.y, acc[1][1]);
            acc[1][2] = fmaf(wv.y, fv.z, acc[1][2]); acc[1][3] = fmaf(wv.y, fv.w, acc[1][3]);
            acc[2][0] = fmaf(wv.z, fv.x, acc[2][0]); acc[2][1] = fmaf(wv.z, fv.y, acc[2][1]);
            acc[2][2] = fmaf(wv.z, fv.z, acc[2][2]); acc[2][3] = fmaf(wv.z, fv.w, acc[2][3]);
            acc[3][0] = fmaf(wv.w, fv.x, acc[3][0]); acc[3][1] = fmaf(wv.w, fv.y, acc[3][1]);
            acc[3][2] = fmaf(wv.w, fv.z, acc[3][2]); acc[3][3] = fmaf(wv.w, fv.w, acc[3][3]);
        }
    }

    const int og0 = oh * 64 + o0;
    const int h = og0 >> 5, d0 = og0 & 31;
    const int ng = nb + nn0;
    if (t == 2) {
        // fragment-order permutation of the 4-key group within its 16-window
        const int off = ng & 15;                      // 0,4,8,12
        const int ng2 = (ng & ~15) + ((off & 4) << 1) + ((off & 8) >> 1);
        #pragma unroll
        for (int i = 0; i < 4; ++i) {
            ushort4 pk;
            pk.x = __builtin_bit_cast(unsigned short, (__bf16)acc[i][0]);
            pk.y = __builtin_bit_cast(unsigned short, (__bf16)acc[i][1]);
            pk.z = __builtin_bit_cast(unsigned short, (__bf16)acc[i][2]);
            pk.w = __builtin_bit_cast(unsigned short, (__bf16)acc[i][3]);
            *reinterpret_cast<ushort4*>(V2 + (size_t)(h * HDIM + d0 + i) * NKEY + m * NTOK + ng2) = pk;
        }
    } else {
        const float sc = (t == 0) ? QSC : 1.0f;
        unsigned short* base = ((t == 0) ? Qb : Kb)
            + (((size_t)(m * NHD + h)) * NTOK + ng) * HDIM + d0;
        #pragma unroll
        for (int j = 0; j < 4; ++j) {
            unsigned short* row = base + (size_t)j * HDIM;
            *reinterpret_cast<unsigned int*>(row)     = pkbf(acc[0][j] * sc, acc[1][j] * sc);
            *reinterpret_cast<unsigned int*>(row + 2) = pkbf(acc[2][j] * sc, acc[3][j] * sc);
        }
    }
}

// ---------------------------------------------------------------------------
// Kernel 2: MFMA cross-modal attention, LDS-staged K/V, conflict-free
// swizzles (verified by bank enumeration):
//   K LDS [64 key][4 c16]: stored chunk c holds global chunk c^((key>>1)&3)
//   V LDS [32 d][8 c16]:   stored chunk c holds global chunk c^(d&7)
// glds writes linearly; the XOR is pre-applied on the global SOURCE address
// and re-applied on ds_read (both-sides rule). Stage-early / drain-late
// double-buffer, 1 barrier/tile. MFMA pairing identical to verified R4-R6.
// Epilogue: LDS transpose -> accT[(ko*4+h)*32+d][q] coalesced, sR sums.
// ---------------------------------------------------------------------------
__global__ __launch_bounds__(512) void attn_kernel(
    const unsigned short* __restrict__ Qb, const unsigned short* __restrict__ Kb,
    const unsigned short* __restrict__ V2,
    float* __restrict__ accT, float* __restrict__ sR)
{
    __shared__ __align__(16) unsigned short smAll[2][2][2][2048]; // 32 KB
    __shared__ __align__(16) float sL[4][2][2][32];               // 2 KB

    const int tid  = threadIdx.x;
    const int lane = tid & 63;
    const int w    = tid >> 6;
    const int qslot = w & 3;
    const int ks    = w >> 2;
    const int l31  = lane & 31;
    const int hi   = lane >> 5;

    const int bid  = blockIdx.x;
    const int slot = bid & 7;
    const int h    = slot >> 1;
    const int ko   = slot & 1;
    const int qb   = bid >> 3;             // 0..53
    const int qtile = qb * 4 + qslot;      // 0..215
    const int qg0  = qtile * 32;
    const int im   = qg0 / NTOK;
    const int n0   = qg0 % NTOK;
    const int km   = ko * 2 + ks;

    // Q fragments (pre-scaled by QSC)
    const unsigned short* qp = Qb + (((size_t)(im * NHD + h)) * NTOK + n0 + l31) * HDIM + hi * 8;
    const bf16x8 qf0 = ldb8(qp);
    const bf16x8 qf1 = ldb8(qp + 16);

    unsigned short* sm = &smAll[ks][0][0][0];   // 8192 shorts per stream

    // --- staging source pointers (inverse-swizzled chunks) ---
    const int rK = qslot * 16 + (lane >> 2);          // K tile row (key)
    const int cK = (lane & 3) ^ ((lane >> 3) & 3);    // global 16B chunk
    const unsigned short* gK = Kb + (((size_t)(km * NHD + h)) * NTOK + rK) * HDIM + cK * 8;
    const int dV = qslot * 8 + (lane >> 3);           // V tile row (d)
    const int cV = (lane & 7) ^ ((lane >> 3) & 7);
    const unsigned short* gV = V2 + ((size_t)(h * HDIM + dV)) * NKEY + km * NTOK + cV * 8;

    // --- LDS read offsets (shorts), swizzle involution applied ---
    const int f31 = (l31 >> 1) & 3;
    const int kA0 = l31 * 32 + ((hi ^ f31) << 3);
    const int kB0 = l31 * 32 + (((2 + hi) ^ f31) << 3);
    const int vbase = l31 * 64;
    const int x7 = l31 & 7;

    f32x16 o_acc;
    #pragma unroll
    for (int r = 0; r < 16; ++r) o_acc[r] = 0.f;
    float s_part = 0.f;
    int buf = 0;

    // prologue: stage tile 0
    glds16(gK, sm + qslot * 512);
    glds16(gV, sm + 2048 + qslot * 512);
    __syncthreads();

    for (int t = 0; t < NT; ++t) {
        if (t + 1 < NT) {
            unsigned short* dst = sm + (buf ^ 1) * 4096;
            glds16(gK + (t + 1) * 2048, dst + qslot * 512);
            glds16(gV + (t + 1) * 64,  dst + 2048 + qslot * 512);
        }
        const unsigned short* Kl = sm + buf * 4096;
        const unsigned short* Vl = Kl + 2048;

        #pragma unroll
        for (int st = 0; st < 2; ++st) {
            bf16x8 k0 = ldb8(Kl + st * 1024 + kA0);
            bf16x8 k1 = ldb8(Kl + st * 1024 + kB0);
            f32x16 c;
            #pragma unroll
            for (int r = 0; r < 16; ++r) c[r] = 0.f;
            c = __builtin_amdgcn_mfma_f32_32x32x16_bf16(k0, qf0, c, 0, 0, 0);
            c = __builtin_amdgcn_mfma_f32_32x32x16_bf16(k1, qf1, c, 0, 0, 0);

            float e[16];
            #pragma unroll
            for (int r = 0; r < 16; ++r) { e[r] = EXP2(c[r]); s_part += e[r]; }
            bf16x8 pa0, pa1;
            #pragma unroll
            for (int j = 0; j < 8; ++j) { pa0[j] = (__bf16)e[j]; pa1[j] = (__bf16)e[8 + j]; }

            // V windows 2st, 2st+1: single b128 each (fragment-ordered V2)
            bf16x8 v0 = ldb8(Vl + vbase + (((4 * st + hi)     ^ x7) << 3));
            bf16x8 v1 = ldb8(Vl + vbase + (((4 * st + 2 + hi) ^ x7) << 3));

            o_acc = __builtin_amdgcn_mfma_f32_32x32x16_bf16(pa0, v0, o_acc, 0, 0, 0);
            o_acc = __builtin_amdgcn_mfma_f32_32x32x16_bf16(pa1, v1, o_acc, 0, 0, 0);
        }
        __syncthreads();
        buf ^= 1;
    }

    // --- combine 2 inner streams in LDS [128 q][33] (padded), transpose out ---
    float* accf = (float*)&smAll[0][0][0][0];    // 128*33*4 = 16.9 KB
    if (ks == 1) {
        #pragma unroll
        for (int r = 0; r < 16; ++r) {
            const int qrow = (r & 3) + 8 * (r >> 2) + 4 * hi;
            accf[(qslot * 32 + qrow) * 33 + l31] = o_acc[r];
        }
    }
    sL[qslot][ks][hi][l31] = s_part;
    __syncthreads();
    if (ks == 0) {
        #pragma unroll
        for (int r = 0; r < 16; ++r) {
            const int qrow = (r & 3) + 8 * (r >> 2) + 4 * hi;
            accf[(qslot * 32 + qrow) * 33 + l31] += o_acc[r];
        }
    }
    __syncthreads();
    {
        const int q  = tid & 127;
        const int d0 = tid >> 7;      // 0..3
        #pragma unroll
        for (int j = 0; j < 8; ++j) {
            const int d = d0 + j * 4;
            accT[((size_t)((ko * 4 + h) * HDIM + d)) * NKEY + (size_t)qb * 128 + q]
                = accf[q * 33 + d];
        }
        if (tid < 128) {
            const int qs = tid >> 5, ql = tid & 31;
            float st = (sL[qs][0][0][ql] + sL[qs][0][1][ql])
                     + (sL[qs][1][0][ql] + sL[qs][1][1][ql]);
            sR[((size_t)(ko * 4 + h)) * NKEY + (size_t)qb * 128 + tid] = st;
        }
    }
}

// ---------------------------------------------------------------------------
// Kernel 3: combine outer key halves + normalize + modality-sum.
// thread per (c,n): fused[c][n] = sum_im (accT[c]+accT[c+128])[im,n] / s
// ---------------------------------------------------------------------------
__global__ __launch_bounds__(256) void norm_kernel(
    const float* __restrict__ accT, const float* __restrict__ sR,
    float* __restrict__ fused)
{
    const int idx = blockIdx.x * 256 + threadIdx.x;  // 0 .. 128*1728-1
    const int c = idx / NTOK;
    const int n = idx % NTOK;
    const int h = c >> 5;
    float acc = 0.f;
    #pragma unroll
    for (int imq = 0; imq < MODS; ++imq) {
        const size_t q = (size_t)imq * NTOK + n;
        const float s = sR[(size_t)h * NKEY + q] + sR[(size_t)(4 + h) * NKEY + q];
        const float a = accT[(size_t)c * NKEY + q] + accT[(size_t)(c + 128) * NKEY + q];
        acc = fmaf(a, 1.0f / s, acc);
    }
    fused[idx] = acc;
}

// ---------------------------------------------------------------------------
// Kernel 4: out-proj (Wout @ fused) + BatchNorm(eval) + ReLU, 2 tokens/thread
// ---------------------------------------------------------------------------
__global__ __launch_bounds__(256) void outproj_kernel(
    const float* __restrict__ fused, const float* __restrict__ Wout,
    const float* __restrict__ gamma, const float* __restrict__ beta,
    const float* __restrict__ mean,  const float* __restrict__ var,
    float* __restrict__ out)
{
    const int idx = blockIdx.x * 256 + threadIdx.x;  // 0 .. 128*864-1
    const int n2 = idx % (NTOK / 2);
    const int o  = idx / (NTOK / 2);
    const float* W     = Wout + (size_t)o * CH;
    const float* fbase = fused + n2 * 2;
    float a0 = 0.f, a1 = 0.f;
    #pragma unroll 8
    for (int c = 0; c < CH; c += 4) {
        float4 w4 = *reinterpret_cast<const float4*>(W + c);
        float2 r0 = *reinterpret_cast<const float2*>(fbase + (size_t)(c + 0) * NTOK);
        float2 r1 = *reinterpret_cast<const float2*>(fbase + (size_t)(c + 1) * NTOK);
        float2 r2 = *reinterpret_cast<const float2*>(fbase + (size_t)(c + 2) * NTOK);
        float2 r3 = *reinterpret_cast<const float2*>(fbase + (size_t)(c + 3) * NTOK);
        a0 = fmaf(w4.x, r0.x, a0); a0 = fmaf(w4.y, r1.x, a0);
        a0 = fmaf(w4.z, r2.x, a0); a0 = fmaf(w4.w, r3.x, a0);
        a1 = fmaf(w4.x, r0.y, a1); a1 = fmaf(w4.y, r1.y, a1);
        a1 = fmaf(w4.z, r2.y, a1); a1 = fmaf(w4.w, r3.y, a1);
    }
    float inv = gamma[o] * rsqrtf(var[o] + 1e-5f);
    float sh  = fmaf(-mean[o], inv, beta[o]);
    float2 y;
    y.x = fmaxf(fmaf(a0, inv, sh), 0.f);
    y.y = fmaxf(fmaf(a1, inv, sh), 0.f);
    *reinterpret_cast<float2*>(out + (size_t)o * NTOK + n2 * 2) = y;
}

// ---------------------------------------------------------------------------
extern "C" void kernel_launch(void* const* d_in, const int* in_sizes, int n_in,
                              void* d_out, int out_size, void* d_ws, size_t ws_size,
                              hipStream_t stream)
{
    const float* f0    = (const float*)d_in[0];
    const float* f1    = (const float*)d_in[1];
    const float* f2    = (const float*)d_in[2];
    const float* f3    = (const float*)d_in[3];
    const float* Wq    = (const float*)d_in[4];
    const float* Wk    = (const float*)d_in[5];
    const float* Wv    = (const float*)d_in[6];
    const float* Wout  = (const float*)d_in[7];
    const float* gamma = (const float*)d_in[8];
    const float* beta  = (const float*)d_in[9];
    const float* mean  = (const float*)d_in[10];
    const float* var   = (const float*)d_in[11];
    float* out = (float*)d_out;

    const size_t QKV = (size_t)MODS * NHD * NTOK * HDIM;   // 884736 elems
    unsigned short* Qb = (unsigned short*)d_ws;
    unsigned short* Kb = Qb + QKV;
    unsigned short* V2 = Kb + QKV;
    float* accT  = (float*)(V2 + QKV);          // [256 rows][6912 q] f32
    float* sR    = accT + (size_t)2 * NHD * HDIM * NKEY;   // [8][6912]
    float* fused = sR + (size_t)2 * NHD * NKEY;            // [CH][NTOK]

    proj_kernel<<<648, 256, 0, stream>>>(f0, f1, f2, f3, Wq, Wk, Wv, Qb, Kb, V2);
    attn_kernel<<<432, 512, 0, stream>>>(Qb, Kb, V2, accT, sR);
    norm_kernel<<<(CH * NTOK) / 256, 256, 0, stream>>>(accT, sR, fused);
    outproj_kernel<<<(CH * NTOK / 2) / 256, 256, 0, stream>>>(
        fused, Wout, gamma, beta, mean, var, out);
}